// Round 9
// baseline (104.845 us; speedup 1.0000x reference)
//
#include <hip/hip_runtime.h>
#include <hip/hip_bf16.h>
#include <stdint.h>

typedef __attribute__((ext_vector_type(8))) short short8;
typedef __attribute__((ext_vector_type(4))) float f32x4;

#define NTHREADS 256
#define DIM 128
#define NH 16
#define HD 8
#define HIDDEN 344
#define HIDP 352          // HIDDEN padded to multiple of 32 (22 col-tiles)
#define BATCH 4
#define SEQ 2048
#define MROWS (BATCH * SEQ)   // 8192
#define LOG2E 1.4426950408889634f

static __device__ __forceinline__ uint16_t f2bf(float f) {
  union { float f; uint32_t u; } v; v.f = f;
  uint32_t r = v.u + 0x7FFFu + ((v.u >> 16) & 1u);
  return (uint16_t)(r >> 16);
}
static __device__ __forceinline__ float fast_exp2(float x) {
#if __has_builtin(__builtin_amdgcn_exp2f)
  return __builtin_amdgcn_exp2f(x);
#else
  return exp2f(x);
#endif
}
// RNE pack: compiler emits v_cvt_pk_bf16_f32
static __device__ __forceinline__ uint32_t pk2(float lo, float hi) {
  union { __hip_bfloat162 b; uint32_t u; } c;
  c.b = __float22bfloat162_rn(make_float2(lo, hi));
  return c.u;
}
// truncating bf16x2 pack: one v_perm_b32 (p >= 0, error <= 2^-8 relative)
static __device__ __forceinline__ uint32_t pkt(float lo, float hi) {
  return __builtin_amdgcn_perm(__builtin_bit_cast(uint32_t, hi),
                               __builtin_bit_cast(uint32_t, lo), 0x07060302u);
}
static __device__ __forceinline__ f32x4 mfma32(short8 a, short8 b, f32x4 c) {
  return __builtin_amdgcn_mfma_f32_16x16x32_bf16(a, b, c, 0, 0, 0);
}

// ------------------------------------------------------------------
// prep: weights -> transposed bf16 Wt[n][k], padded where needed.
// wq rows pre-scaled by log2(e) so attention uses exp2 directly.
// w1t/w3t padded to 384 rows (zeros), w2t padded to 352 k (zeros).
// ------------------------------------------------------------------
__global__ __launch_bounds__(256) void prep_kernel(
    const float* __restrict__ wq,
    const float* __restrict__ wk, const float* __restrict__ wv,
    const float* __restrict__ wo, const float* __restrict__ w1,
    const float* __restrict__ w3, const float* __restrict__ w2,
    uint16_t* __restrict__ qkv_t,
    uint16_t* __restrict__ wo_t,  uint16_t* __restrict__ w1_t,
    uint16_t* __restrict__ w3_t,  uint16_t* __restrict__ w2_t)
{
  const int nt  = gridDim.x * blockDim.x;
  const int tid = blockIdx.x * blockDim.x + threadIdx.x;
  for (int i = tid; i < 384 * 128; i += nt) {
    int n = i >> 7, k = i & 127;
    const float* w = (n < 128) ? wq : ((n < 256) ? wk : wv);
    const float s = (n < 128) ? LOG2E : 1.0f;
    qkv_t[i] = f2bf(w[k * 128 + (n & 127)] * s);
  }
  for (int i = tid; i < 128 * 128; i += nt) {
    int n = i >> 7, k = i & 127;
    wo_t[i] = f2bf(wo[k * 128 + n]);
  }
  for (int i = tid; i < 384 * 128; i += nt) {
    int n = i >> 7, k = i & 127;
    w1_t[i] = (n < HIDDEN) ? f2bf(w1[k * HIDDEN + n]) : (uint16_t)0;
    w3_t[i] = (n < HIDDEN) ? f2bf(w3[k * HIDDEN + n]) : (uint16_t)0;
  }
  for (int i = tid; i < 128 * HIDP; i += nt) {
    int n = i / HIDP, k = i - n * HIDP;
    w2_t[i] = (k < HIDDEN) ? f2bf(w2[k * 128 + n]) : (uint16_t)0;
  }
}

// ------------------------------------------------------------------
// Register-streaming QKV GEMM (r7-proven): no LDS, no barriers.
// Block = 4 waves; wave computes 16 rows x 64 cols; A fp32 -> bf16.
// col<128 -> q_buf; 128..255 -> Kc[b,h][s][8]; 256..383 -> Vt[b,h*8+d][s]
// ------------------------------------------------------------------
__global__ __launch_bounds__(256, 4) void qkv_gemm(
    const float* __restrict__ Av, const uint16_t* __restrict__ B1t,
    uint16_t* __restrict__ outb,
    uint16_t* __restrict__ kc_o, uint16_t* __restrict__ vt_o)
{
  const int tid = threadIdx.x;
  const int w = tid >> 6, l = tid & 63;
  const int lg = l >> 4, lm = l & 15;
  const int row0 = blockIdx.x * 64 + w * 16;
  const int col0 = blockIdx.y * 64;

  short8 af[4];
  const float* Af = Av + (size_t)(row0 + lm) * 128 + lg * 8;
#pragma unroll
  for (int ks = 0; ks < 4; ++ks) {
    const f32x4 a0 = *(const f32x4*)(Af + ks * 32);
    const f32x4 a1 = *(const f32x4*)(Af + ks * 32 + 4);
    union { uint32_t u[4]; short8 s8; } cv;
    cv.u[0] = pk2(a0[0], a0[1]); cv.u[1] = pk2(a0[2], a0[3]);
    cv.u[2] = pk2(a1[0], a1[1]); cv.u[3] = pk2(a1[2], a1[3]);
    af[ks] = cv.s8;
  }

  f32x4 acc[4];
#pragma unroll
  for (int t = 0; t < 4; ++t) acc[t] = (f32x4){0.f, 0.f, 0.f, 0.f};

#pragma unroll
  for (int t = 0; t < 4; ++t) {
    const uint16_t* Bp = B1t + (size_t)(col0 + t * 16 + lm) * 128 + lg * 8;
#pragma unroll
    for (int ks = 0; ks < 4; ++ks)
      acc[t] = mfma32(af[ks], *(const short8*)(Bp + ks * 32), acc[t]);
  }

#pragma unroll
  for (int t = 0; t < 4; ++t) {
#pragma unroll
    for (int r = 0; r < 4; ++r) {
      const int row = row0 + lg * 4 + r;
      const int col = col0 + t * 16 + lm;
      const float v = acc[t][r];
      const int bb = row >> 11, ss = row & 2047;
      if (col < 128) {
        outb[(size_t)row * 128 + col] = f2bf(v);            // Q (pre-scaled)
      } else if (col < 256) {
        const int c = col - 128;
        kc_o[((size_t)((bb << 4) + (c >> 3)) * SEQ + ss) * 8 + (c & 7)] = f2bf(v);
      } else {
        const int c = col - 256;
        vt_o[((size_t)(bb * 128 + c)) * SEQ + ss] = f2bf(v);
      }
    }
  }
}

// ------------------------------------------------------------------
// Flash attention, 2-way key-split. Block = (b, h, 64 q rows); 4 waves:
// wave w -> rows grp=(w>>1)*32 (2 tiles of 16), keys half kh=(w&1)*1024.
// r5-proven pipelined body (VGPR ~60 -- do NOT tighten launch_bounds;
// occupancy comes from grid 2048 = 8 blocks/CU at VGPR<=64).
// No-max softmax => partials merge by pure addition via 8KB LDS.
// QK^T swapped (mfma 16x16x32), permuted K rows so the QK D-layout IS
// the PV B-fragment layout. p = exp2(score). PV A = Vt rows on lm;
// lm==8 carries a ones-row -> acc row 8 = sum(p) (adds across halves).
// ------------------------------------------------------------------
__global__ __launch_bounds__(256, 4) void attn_kernel(
    const uint16_t* __restrict__ qb,   // [MROWS][128]  (pre-scaled Q)
    const uint16_t* __restrict__ kc,   // [B*NH][SEQ][8]
    const uint16_t* __restrict__ vt,   // [B*NH*8][SEQ]
    uint16_t* __restrict__ attn_o)     // [MROWS][128]
{
  __shared__ __attribute__((aligned(16))) float part[4][64][8];

  const int tid = threadIdx.x;
  const int w = tid >> 6, l = tid & 63;
  const int lg = l >> 4, lm = l & 15;
  int bid = blockIdx.x;
  bid = (bid & 7) * 256 + (bid >> 3);   // bijective XCD swizzle (2048 % 8 == 0)
  const int qc = bid & 31;              // SEQ/64 = 32 q-chunks
  const int bh = bid >> 5;
  const int b = bh >> 4, h = bh & 15;
  const int grp = w >> 1, kh = w & 1;
  const int q0 = qc * 64 + grp * 32;

  const short8 zero8 = {0, 0, 0, 0, 0, 0, 0, 0};
  const f32x4 zero4 = {0.f, 0.f, 0.f, 0.f};
  const short ob = (short)0x3F80;  // bf16 1.0
  const short8 ones8 = {ob, ob, ob, ob, ob, ob, ob, ob};

  // Q fragments (once): B-frag lanes lg==0 hold Q[q][d=0..7]
  short8 qf0 = zero8, qf1 = zero8;
  if (lg == 0) {
    qf0 = *(const short8*)(qb + (size_t)(b * SEQ + q0 + lm) * DIM + h * HD);
    qf1 = *(const short8*)(qb + (size_t)(b * SEQ + q0 + 16 + lm) * DIM + h * HD);
  }

  // wave covers keys [kh*1024, kh*1024+1024): 16 chunks of 64
  // permuted K base: tile-A row lm <- key 8*(lm>>2)+(lm&3)
  const uint16_t* kp = kc + (size_t)bh * SEQ * HD +
                       (kh * 1024 + 8 * (lm >> 2) + (lm & 3)) * HD;
  // V: A-frag lane (lg, lm<8) holds Vt[d=lm][key + 8*lg + j]
  const uint16_t* vp = vt + (size_t)(bh * HD + (lm & 7)) * SEQ + kh * 1024 + lg * 8;

  // named K/V double buffers
  short8 ka0 = zero8, ka1 = zero8, ka2 = zero8, ka3 = zero8;
  short8 kb0 = zero8, kb1 = zero8, kb2 = zero8, kb3 = zero8;
  const short8 vinit = (lm == 8) ? ones8 : zero8;
  short8 va0 = vinit, va1 = vinit, vb0 = vinit, vb1 = vinit;

  f32x4 o00 = zero4, o01 = zero4, o10 = zero4, o11 = zero4;

#define LK(R0, R1, R2, R3)                         \
  do { if (lg == 0) {                              \
    R0 = *(const short8*)(kp);                     \
    R1 = *(const short8*)(kp + 32);                \
    R2 = *(const short8*)(kp + 256);               \
    R3 = *(const short8*)(kp + 288); }             \
    kp += 512; } while (0)

#define LV(R0, R1)                                 \
  do { if (lm < HD) {                              \
    R0 = *(const short8*)(vp);                     \
    R1 = *(const short8*)(vp + 32); }              \
    vp += 64; } while (0)

#define PACKP(SA, SB, OUT)                                  \
  do { union { uint32_t u[4]; short8 s; } _t;               \
    _t.u[0] = pkt(fast_exp2(SA[0]), fast_exp2(SA[1]));      \
    _t.u[1] = pkt(fast_exp2(SA[2]), fast_exp2(SA[3]));      \
    _t.u[2] = pkt(fast_exp2(SB[0]), fast_exp2(SB[1]));      \
    _t.u[3] = pkt(fast_exp2(SB[2]), fast_exp2(SB[3]));      \
    OUT = _t.s; } while (0)

#define COMPUTE(K0, K1, K2, K3, V0, V1)                     \
  do {                                                      \
    f32x4 s0, s1, s2, s3, s4, s5, s6, s7;                   \
    __builtin_amdgcn_s_setprio(1);                          \
    s0 = mfma32(K0, qf0, zero4);                            \
    s1 = mfma32(K1, qf0, zero4);                            \
    s2 = mfma32(K2, qf0, zero4);                            \
    s3 = mfma32(K3, qf0, zero4);                            \
    s4 = mfma32(K0, qf1, zero4);                            \
    s5 = mfma32(K1, qf1, zero4);                            \
    s6 = mfma32(K2, qf1, zero4);                            \
    s7 = mfma32(K3, qf1, zero4);                            \
    __builtin_amdgcn_s_setprio(0);                          \
    short8 p0, p1, p2, p3;                                  \
    PACKP(s0, s1, p0);                                      \
    PACKP(s2, s3, p1);                                      \
    PACKP(s4, s5, p2);                                      \
    PACKP(s6, s7, p3);                                      \
    __builtin_amdgcn_s_setprio(1);                          \
    o00 = mfma32(V0, p0, o00);                              \
    o01 = mfma32(V1, p1, o01);                              \
    o10 = mfma32(V0, p2, o10);                              \
    o11 = mfma32(V1, p3, o11);                              \
    __builtin_amdgcn_s_setprio(0);                          \
  } while (0)

  // software pipeline: 16 chunks of 64 keys; load i+1 before compute i
  LK(ka0, ka1, ka2, ka3); LV(va0, va1);
#pragma unroll 1
  for (int it = 0; it < 7; ++it) {
    LK(kb0, kb1, kb2, kb3); LV(vb0, vb1);
    COMPUTE(ka0, ka1, ka2, ka3, va0, va1);
    LK(ka0, ka1, ka2, ka3); LV(va0, va1);
    COMPUTE(kb0, kb1, kb2, kb3, vb0, vb1);
  }
  LK(kb0, kb1, kb2, kb3); LV(vb0, vb1);
  COMPUTE(ka0, ka1, ka2, ka3, va0, va1);
  COMPUTE(kb0, kb1, kb2, kb3, vb0, vb1);

#undef LK
#undef LV
#undef PACKP
#undef COMPUTE

  const f32x4 accA = o00 + o01;   // tile 0 (rows q0 + lm), this key half
  const f32x4 accB = o10 + o11;   // tile 1 (rows q0 + 16 + lm)
  *(f32x4*)&part[w][l][0] = accA;
  *(f32x4*)&part[w][l][4] = accB;
  __syncthreads();

  // waves 0 and 2 merge the two key-halves for their row group
  if (kh == 0) {
    const f32x4 mA = *(const f32x4*)&part[w][l][0] + *(const f32x4*)&part[w + 1][l][0];
    const f32x4 mB = *(const f32x4*)&part[w][l][4] + *(const f32x4*)&part[w + 1][l][4];
    // row 8 (lane 32+lm, reg 0) holds sum(p) for q=lm
    const float invA = 1.0f / __shfl(mA[0], 32 + lm);
    const float invB = 1.0f / __shfl(mB[0], 32 + lm);
    if (lg < 2) {
      const size_t oA = (size_t)(b * SEQ + q0 + lm) * DIM + h * HD + lg * 4;
      *(uint32_t*)(attn_o + oA)     = pk2(mA[0] * invA, mA[1] * invA);
      *(uint32_t*)(attn_o + oA + 2) = pk2(mA[2] * invA, mA[3] * invA);
      const size_t oB = (size_t)(b * SEQ + q0 + 16 + lm) * DIM + h * HD + lg * 4;
      *(uint32_t*)(attn_o + oB)     = pk2(mB[0] * invB, mB[1] * invB);
      *(uint32_t*)(attn_o + oB + 2) = pk2(mB[2] * invB, mB[3] * invB);
    }
  }
}

// ------------------------------------------------------------------
// Fused post-attention chain (row-local): h = x + attn@wo;
// out = h + silu(h@w1)*(h@w3) @ w2.  Block = 32 rows, 2 waves; each
// wave owns 16 rows end-to-end (wave-private LDS, NO barriers).
// h kept fp32 in registers (D-layout) for the final add; transposed to
// A-frag layout via LDS (padded strides 136/360 break bank conflicts).
// ------------------------------------------------------------------
__global__ __launch_bounds__(128) void ffn_kernel(
    const uint16_t* __restrict__ attn_o,  // [MROWS][128] bf16
    const float* __restrict__ x,          // [MROWS][128] fp32
    const uint16_t* __restrict__ wo_t,    // [128][128]
    const uint16_t* __restrict__ w1_t,    // [384][128] (rows>=344 zero)
    const uint16_t* __restrict__ w3_t,    // [384][128]
    const uint16_t* __restrict__ w2_t,    // [128][352] (k>=344 zero)
    float* __restrict__ out)              // [MROWS][128] fp32
{
  __shared__ __attribute__((aligned(16))) uint16_t h_l[2][16][136];
  __shared__ __attribute__((aligned(16))) uint16_t u_l[2][16][360];

  const int tid = threadIdx.x;
  const int w = tid >> 6, l = tid & 63;
  const int lg = l >> 4, lm = l & 15;
  const int R0 = blockIdx.x * 32 + w * 16;

  // ---- stage A: h = x + attn @ wo ----
  short8 af[4];
  const uint16_t* Ap = attn_o + (size_t)(R0 + lm) * 128 + lg * 8;
#pragma unroll
  for (int ks = 0; ks < 4; ++ks) af[ks] = *(const short8*)(Ap + ks * 32);

  float hreg[8][4];
#pragma unroll
  for (int t = 0; t < 8; ++t) {
    f32x4 acc = (f32x4){0.f, 0.f, 0.f, 0.f};
    const uint16_t* Bp = wo_t + (size_t)(t * 16 + lm) * 128 + lg * 8;
#pragma unroll
    for (int ks = 0; ks < 4; ++ks)
      acc = mfma32(af[ks], *(const short8*)(Bp + ks * 32), acc);
#pragma unroll
    for (int r = 0; r < 4; ++r) {
      const float h = acc[r] + x[(size_t)(R0 + lg * 4 + r) * 128 + t * 16 + lm];
      hreg[t][r] = h;
      h_l[w][lg * 4 + r][t * 16 + lm] = f2bf(h);
    }
  }

  // wave-private LDS: compiler inserts lgkmcnt; no barrier needed
  short8 af2[4];
#pragma unroll
  for (int ks = 0; ks < 4; ++ks)
    af2[ks] = *(const short8*)&h_l[w][lm][ks * 32 + lg * 8];

  // ---- stage B: u = silu(h@w1) * (h@w3), bf16 into u_l ----
#pragma unroll 2
  for (int ct = 0; ct < 22; ++ct) {
    f32x4 ag = (f32x4){0.f, 0.f, 0.f, 0.f};
    f32x4 ae = (f32x4){0.f, 0.f, 0.f, 0.f};
    const uint16_t* B1p = w1_t + (size_t)(ct * 16 + lm) * 128 + lg * 8;
    const uint16_t* B3p = w3_t + (size_t)(ct * 16 + lm) * 128 + lg * 8;
#pragma unroll
    for (int ks = 0; ks < 4; ++ks) {
      ag = mfma32(af2[ks], *(const short8*)(B1p + ks * 32), ag);
      ae = mfma32(af2[ks], *(const short8*)(B3p + ks * 32), ae);
    }
#pragma unroll
    for (int r = 0; r < 4; ++r) {
      const float g = ag[r];
      const float u = g / (1.f + __expf(-g)) * ae[r];
      u_l[w][lg * 4 + r][ct * 16 + lm] = f2bf(u);
    }
  }

  short8 af3[11];
#pragma unroll
  for (int k2 = 0; k2 < 11; ++k2)
    af3[k2] = *(const short8*)&u_l[w][lm][k2 * 32 + lg * 8];

  // ---- stage C: out = h + u @ w2 ----
#pragma unroll
  for (int t = 0; t < 8; ++t) {
    f32x4 acc = (f32x4){0.f, 0.f, 0.f, 0.f};
    const uint16_t* Bp = w2_t + (size_t)(t * 16 + lm) * HIDP + lg * 8;
#pragma unroll
    for (int k2 = 0; k2 < 11; ++k2)
      acc = mfma32(af3[k2], *(const short8*)(Bp + k2 * 32), acc);
#pragma unroll
    for (int r = 0; r < 4; ++r)
      out[(size_t)(R0 + lg * 4 + r) * 128 + t * 16 + lm] = hreg[t][r] + acc[r];
  }
}

// ------------------------------------------------------------------
extern "C" void kernel_launch(void* const* d_in, const int* in_sizes, int n_in,
                              void* d_out, int out_size, void* d_ws, size_t ws_size,
                              hipStream_t stream) {
  const float* x  = (const float*)d_in[0];
  const float* wq = (const float*)d_in[1];
  const float* wk = (const float*)d_in[2];
  const float* wv = (const float*)d_in[3];
  const float* wo = (const float*)d_in[4];
  const float* w1 = (const float*)d_in[5];
  const float* w3 = (const float*)d_in[6];
  const float* w2 = (const float*)d_in[7];
  float* out = (float*)d_out;

  char* ws = (char*)d_ws;
  size_t off = 0;
  auto alloc = [&](size_t bytes) {
    size_t o = off;
    off += (bytes + 255) & ~(size_t)255;
    return o;
  };
  uint16_t* qkv_t  = (uint16_t*)(ws + alloc(384 * 128 * 2));
  uint16_t* wo_t   = (uint16_t*)(ws + alloc(128 * 128 * 2));
  uint16_t* w1_t   = (uint16_t*)(ws + alloc(384 * 128 * 2));
  uint16_t* w3_t   = (uint16_t*)(ws + alloc(384 * 128 * 2));
  uint16_t* w2_t   = (uint16_t*)(ws + alloc(128 * HIDP * 2));
  uint16_t* q_buf  = (uint16_t*)(ws + alloc((size_t)MROWS * DIM * 2));
  uint16_t* kc_b   = (uint16_t*)(ws + alloc((size_t)MROWS * DIM * 2));
  uint16_t* vt_b   = (uint16_t*)(ws + alloc((size_t)MROWS * DIM * 2));
  uint16_t* attn_o = (uint16_t*)(ws + alloc((size_t)MROWS * DIM * 2));

  prep_kernel<<<512, 256, 0, stream>>>(wq, wk, wv, wo, w1, w3, w2,
                                       qkv_t, wo_t, w1_t, w3_t, w2_t);
  // qkv = x @ [wq*log2e | wk | wv] -> q_buf, Kc, Vt
  qkv_gemm<<<dim3(MROWS / 64, 6), 256, 0, stream>>>(
      x, qkv_t, q_buf, kc_b, vt_b);
  // flash attention: 2048 blocks (8/CU), 2-way key split
  attn_kernel<<<dim3(BATCH * NH * (SEQ / 64)), 256, 0, stream>>>(
      q_buf, kc_b, vt_b, attn_o);
  // fused: h = x + attn@wo; out = h + silu(h@w1)*(h@w3)@w2
  ffn_kernel<<<dim3(MROWS / 32), 128, 0, stream>>>(
      attn_o, x, wo_t, w1_t, w3_t, w2_t, out);
}

// Round 10
// 77.995 us; speedup vs baseline: 1.3443x; 1.3443x over previous
//
#include <hip/hip_runtime.h>
#include <hip/hip_bf16.h>
#include <stdint.h>

typedef __attribute__((ext_vector_type(8))) short short8;
typedef __attribute__((ext_vector_type(4))) float f32x4;

#define NTHREADS 256
#define DIM 128
#define NH 16
#define HD 8
#define HIDDEN 344
#define HIDP 352          // HIDDEN padded to multiple of 32 (22 col-tiles)
#define BATCH 4
#define SEQ 2048
#define MROWS (BATCH * SEQ)   // 8192
#define LOG2E 1.4426950408889634f

static __device__ __forceinline__ uint16_t f2bf(float f) {
  union { float f; uint32_t u; } v; v.f = f;
  uint32_t r = v.u + 0x7FFFu + ((v.u >> 16) & 1u);
  return (uint16_t)(r >> 16);
}
static __device__ __forceinline__ float fast_exp2(float x) {
#if __has_builtin(__builtin_amdgcn_exp2f)
  return __builtin_amdgcn_exp2f(x);
#else
  return exp2f(x);
#endif
}
// RNE pack: compiler emits v_cvt_pk_bf16_f32
static __device__ __forceinline__ uint32_t pk2(float lo, float hi) {
  union { __hip_bfloat162 b; uint32_t u; } c;
  c.b = __float22bfloat162_rn(make_float2(lo, hi));
  return c.u;
}
// truncating bf16x2 pack: one v_perm_b32 (p >= 0, error <= 2^-8 relative)
static __device__ __forceinline__ uint32_t pkt(float lo, float hi) {
  return __builtin_amdgcn_perm(__builtin_bit_cast(uint32_t, hi),
                               __builtin_bit_cast(uint32_t, lo), 0x07060302u);
}
static __device__ __forceinline__ f32x4 mfma32(short8 a, short8 b, f32x4 c) {
  return __builtin_amdgcn_mfma_f32_16x16x32_bf16(a, b, c, 0, 0, 0);
}

// ------------------------------------------------------------------
// prep: weights -> transposed bf16 Wt[n][k], padded where needed.
// wq rows pre-scaled by log2(e) so attention uses exp2 directly.
// w1t/w3t padded to 384 rows (zeros), w2t padded to 352 k (zeros).
// ------------------------------------------------------------------
__global__ __launch_bounds__(256) void prep_kernel(
    const float* __restrict__ wq,
    const float* __restrict__ wk, const float* __restrict__ wv,
    const float* __restrict__ wo, const float* __restrict__ w1,
    const float* __restrict__ w3, const float* __restrict__ w2,
    uint16_t* __restrict__ qkv_t,
    uint16_t* __restrict__ wo_t,  uint16_t* __restrict__ w1_t,
    uint16_t* __restrict__ w3_t,  uint16_t* __restrict__ w2_t)
{
  const int nt  = gridDim.x * blockDim.x;
  const int tid = blockIdx.x * blockDim.x + threadIdx.x;
  for (int i = tid; i < 384 * 128; i += nt) {
    int n = i >> 7, k = i & 127;
    const float* w = (n < 128) ? wq : ((n < 256) ? wk : wv);
    const float s = (n < 128) ? LOG2E : 1.0f;
    qkv_t[i] = f2bf(w[k * 128 + (n & 127)] * s);
  }
  for (int i = tid; i < 128 * 128; i += nt) {
    int n = i >> 7, k = i & 127;
    wo_t[i] = f2bf(wo[k * 128 + n]);
  }
  for (int i = tid; i < 384 * 128; i += nt) {
    int n = i >> 7, k = i & 127;
    w1_t[i] = (n < HIDDEN) ? f2bf(w1[k * HIDDEN + n]) : (uint16_t)0;
    w3_t[i] = (n < HIDDEN) ? f2bf(w3[k * HIDDEN + n]) : (uint16_t)0;
  }
  for (int i = tid; i < 128 * HIDP; i += nt) {
    int n = i / HIDP, k = i - n * HIDP;
    w2_t[i] = (k < HIDDEN) ? f2bf(w2[k * 128 + n]) : (uint16_t)0;
  }
}

// ------------------------------------------------------------------
// Register-streaming QKV GEMM (r7-proven): no LDS, no barriers.
// Block = 4 waves; wave computes 16 rows x 64 cols; A fp32 -> bf16.
// col<128 -> q_buf; 128..255 -> Kc[b,h][s][8]; 256..383 -> Vt[b,h*8+d][s]
// ------------------------------------------------------------------
__global__ __launch_bounds__(256, 4) void qkv_gemm(
    const float* __restrict__ Av, const uint16_t* __restrict__ B1t,
    uint16_t* __restrict__ outb,
    uint16_t* __restrict__ kc_o, uint16_t* __restrict__ vt_o)
{
  const int tid = threadIdx.x;
  const int w = tid >> 6, l = tid & 63;
  const int lg = l >> 4, lm = l & 15;
  const int row0 = blockIdx.x * 64 + w * 16;
  const int col0 = blockIdx.y * 64;

  short8 af[4];
  const float* Af = Av + (size_t)(row0 + lm) * 128 + lg * 8;
#pragma unroll
  for (int ks = 0; ks < 4; ++ks) {
    const f32x4 a0 = *(const f32x4*)(Af + ks * 32);
    const f32x4 a1 = *(const f32x4*)(Af + ks * 32 + 4);
    union { uint32_t u[4]; short8 s8; } cv;
    cv.u[0] = pk2(a0[0], a0[1]); cv.u[1] = pk2(a0[2], a0[3]);
    cv.u[2] = pk2(a1[0], a1[1]); cv.u[3] = pk2(a1[2], a1[3]);
    af[ks] = cv.s8;
  }

  f32x4 acc[4];
#pragma unroll
  for (int t = 0; t < 4; ++t) acc[t] = (f32x4){0.f, 0.f, 0.f, 0.f};

#pragma unroll
  for (int t = 0; t < 4; ++t) {
    const uint16_t* Bp = B1t + (size_t)(col0 + t * 16 + lm) * 128 + lg * 8;
#pragma unroll
    for (int ks = 0; ks < 4; ++ks)
      acc[t] = mfma32(af[ks], *(const short8*)(Bp + ks * 32), acc[t]);
  }

#pragma unroll
  for (int t = 0; t < 4; ++t) {
#pragma unroll
    for (int r = 0; r < 4; ++r) {
      const int row = row0 + lg * 4 + r;
      const int col = col0 + t * 16 + lm;
      const float v = acc[t][r];
      const int bb = row >> 11, ss = row & 2047;
      if (col < 128) {
        outb[(size_t)row * 128 + col] = f2bf(v);            // Q (pre-scaled)
      } else if (col < 256) {
        const int c = col - 128;
        kc_o[((size_t)((bb << 4) + (c >> 3)) * SEQ + ss) * 8 + (c & 7)] = f2bf(v);
      } else {
        const int c = col - 256;
        vt_o[((size_t)(bb * 128 + c)) * SEQ + ss] = f2bf(v);
      }
    }
  }
}

// ------------------------------------------------------------------
// Flash attention, 2-way key-split (r9). Block = (b, h, 64 q rows);
// 4 waves: wave w -> rows grp=(w>>1)*32, keys half kh=(w&1)*1024.
// r5-proven pipelined body (VGPR ~60 -- do NOT tighten launch_bounds).
// No-max softmax => partials merge by pure addition via 8KB LDS.
// ------------------------------------------------------------------
__global__ __launch_bounds__(256, 4) void attn_kernel(
    const uint16_t* __restrict__ qb,   // [MROWS][128]  (pre-scaled Q)
    const uint16_t* __restrict__ kc,   // [B*NH][SEQ][8]
    const uint16_t* __restrict__ vt,   // [B*NH*8][SEQ]
    uint16_t* __restrict__ attn_o)     // [MROWS][128]
{
  __shared__ __attribute__((aligned(16))) float part[4][64][8];

  const int tid = threadIdx.x;
  const int w = tid >> 6, l = tid & 63;
  const int lg = l >> 4, lm = l & 15;
  int bid = blockIdx.x;
  bid = (bid & 7) * 256 + (bid >> 3);   // bijective XCD swizzle (2048 % 8 == 0)
  const int qc = bid & 31;              // SEQ/64 = 32 q-chunks
  const int bh = bid >> 5;
  const int b = bh >> 4, h = bh & 15;
  const int grp = w >> 1, kh = w & 1;
  const int q0 = qc * 64 + grp * 32;

  const short8 zero8 = {0, 0, 0, 0, 0, 0, 0, 0};
  const f32x4 zero4 = {0.f, 0.f, 0.f, 0.f};
  const short ob = (short)0x3F80;  // bf16 1.0
  const short8 ones8 = {ob, ob, ob, ob, ob, ob, ob, ob};

  // Q fragments (once): B-frag lanes lg==0 hold Q[q][d=0..7]
  short8 qf0 = zero8, qf1 = zero8;
  if (lg == 0) {
    qf0 = *(const short8*)(qb + (size_t)(b * SEQ + q0 + lm) * DIM + h * HD);
    qf1 = *(const short8*)(qb + (size_t)(b * SEQ + q0 + 16 + lm) * DIM + h * HD);
  }

  // wave covers keys [kh*1024, kh*1024+1024): 16 chunks of 64
  // permuted K base: tile-A row lm <- key 8*(lm>>2)+(lm&3)
  const uint16_t* kp = kc + (size_t)bh * SEQ * HD +
                       (kh * 1024 + 8 * (lm >> 2) + (lm & 3)) * HD;
  // V: A-frag lane (lg, lm<8) holds Vt[d=lm][key + 8*lg + j]
  const uint16_t* vp = vt + (size_t)(bh * HD + (lm & 7)) * SEQ + kh * 1024 + lg * 8;

  // named K/V double buffers
  short8 ka0 = zero8, ka1 = zero8, ka2 = zero8, ka3 = zero8;
  short8 kb0 = zero8, kb1 = zero8, kb2 = zero8, kb3 = zero8;
  const short8 vinit = (lm == 8) ? ones8 : zero8;
  short8 va0 = vinit, va1 = vinit, vb0 = vinit, vb1 = vinit;

  f32x4 o00 = zero4, o01 = zero4, o10 = zero4, o11 = zero4;

#define LK(R0, R1, R2, R3)                         \
  do { if (lg == 0) {                              \
    R0 = *(const short8*)(kp);                     \
    R1 = *(const short8*)(kp + 32);                \
    R2 = *(const short8*)(kp + 256);               \
    R3 = *(const short8*)(kp + 288); }             \
    kp += 512; } while (0)

#define LV(R0, R1)                                 \
  do { if (lm < HD) {                              \
    R0 = *(const short8*)(vp);                     \
    R1 = *(const short8*)(vp + 32); }              \
    vp += 64; } while (0)

#define PACKP(SA, SB, OUT)                                  \
  do { union { uint32_t u[4]; short8 s; } _t;               \
    _t.u[0] = pkt(fast_exp2(SA[0]), fast_exp2(SA[1]));      \
    _t.u[1] = pkt(fast_exp2(SA[2]), fast_exp2(SA[3]));      \
    _t.u[2] = pkt(fast_exp2(SB[0]), fast_exp2(SB[1]));      \
    _t.u[3] = pkt(fast_exp2(SB[2]), fast_exp2(SB[3]));      \
    OUT = _t.s; } while (0)

#define COMPUTE(K0, K1, K2, K3, V0, V1)                     \
  do {                                                      \
    f32x4 s0, s1, s2, s3, s4, s5, s6, s7;                   \
    __builtin_amdgcn_s_setprio(1);                          \
    s0 = mfma32(K0, qf0, zero4);                            \
    s1 = mfma32(K1, qf0, zero4);                            \
    s2 = mfma32(K2, qf0, zero4);                            \
    s3 = mfma32(K3, qf0, zero4);                            \
    s4 = mfma32(K0, qf1, zero4);                            \
    s5 = mfma32(K1, qf1, zero4);                            \
    s6 = mfma32(K2, qf1, zero4);                            \
    s7 = mfma32(K3, qf1, zero4);                            \
    __builtin_amdgcn_s_setprio(0);                          \
    short8 p0, p1, p2, p3;                                  \
    PACKP(s0, s1, p0);                                      \
    PACKP(s2, s3, p1);                                      \
    PACKP(s4, s5, p2);                                      \
    PACKP(s6, s7, p3);                                      \
    __builtin_amdgcn_s_setprio(1);                          \
    o00 = mfma32(V0, p0, o00);                              \
    o01 = mfma32(V1, p1, o01);                              \
    o10 = mfma32(V0, p2, o10);                              \
    o11 = mfma32(V1, p3, o11);                              \
    __builtin_amdgcn_s_setprio(0);                          \
  } while (0)

  // software pipeline: 16 chunks of 64 keys; load i+1 before compute i
  LK(ka0, ka1, ka2, ka3); LV(va0, va1);
#pragma unroll 1
  for (int it = 0; it < 7; ++it) {
    LK(kb0, kb1, kb2, kb3); LV(vb0, vb1);
    COMPUTE(ka0, ka1, ka2, ka3, va0, va1);
    LK(ka0, ka1, ka2, ka3); LV(va0, va1);
    COMPUTE(kb0, kb1, kb2, kb3, vb0, vb1);
  }
  LK(kb0, kb1, kb2, kb3); LV(vb0, vb1);
  COMPUTE(ka0, ka1, ka2, ka3, va0, va1);
  COMPUTE(kb0, kb1, kb2, kb3, vb0, vb1);

#undef LK
#undef LV
#undef PACKP
#undef COMPUTE

  const f32x4 accA = o00 + o01;   // tile 0 (rows q0 + lm), this key half
  const f32x4 accB = o10 + o11;   // tile 1 (rows q0 + 16 + lm)
  *(f32x4*)&part[w][l][0] = accA;
  *(f32x4*)&part[w][l][4] = accB;
  __syncthreads();

  // waves 0 and 2 merge the two key-halves for their row group
  if (kh == 0) {
    const f32x4 mA = *(const f32x4*)&part[w][l][0] + *(const f32x4*)&part[w + 1][l][0];
    const f32x4 mB = *(const f32x4*)&part[w][l][4] + *(const f32x4*)&part[w + 1][l][4];
    // row 8 (lane 32+lm, reg 0) holds sum(p) for q=lm
    const float invA = 1.0f / __shfl(mA[0], 32 + lm);
    const float invB = 1.0f / __shfl(mB[0], 32 + lm);
    if (lg < 2) {
      const size_t oA = (size_t)(b * SEQ + q0 + lm) * DIM + h * HD + lg * 4;
      *(uint32_t*)(attn_o + oA)     = pk2(mA[0] * invA, mA[1] * invA);
      *(uint32_t*)(attn_o + oA + 2) = pk2(mA[2] * invA, mA[3] * invA);
      const size_t oB = (size_t)(b * SEQ + q0 + 16 + lm) * DIM + h * HD + lg * 4;
      *(uint32_t*)(attn_o + oB)     = pk2(mB[0] * invB, mB[1] * invB);
      *(uint32_t*)(attn_o + oB + 2) = pk2(mB[2] * invB, mB[3] * invB);
    }
  }
}

// ------------------------------------------------------------------
// Fused post-attention chain, COLUMN-SPLIT for occupancy (r9 lesson:
// 32-row/128-thread blocks gave 1 block/CU = 0.5 waves/SIMD, 4.9% occ).
// Block = 16 rows x 8 waves (512 thr); grid = MROWS/16 = 512 blocks
// = 2 blocks/CU = 16 waves/CU. Waves split COLUMN tiles per stage:
//   A: h = x + attn@wo      -> wave w does col-tile w (of 8); h -> LDS
//   B: u = silu(h@w1)*(h@w3)-> wave w does ct = w, w+8, w+16 (<22)
//   C: out = h + u@w2       -> wave w does col-tile w, K=352 from LDS
// hreg keeps h for the final add (same tile owner in A and C).
// 2 barriers; LDS 15.9 KB (strides 136/360 break bank conflicts).
// ------------------------------------------------------------------
__global__ __launch_bounds__(512) void ffn_kernel(
    const uint16_t* __restrict__ attn_o,  // [MROWS][128] bf16
    const float* __restrict__ x,          // [MROWS][128] fp32
    const uint16_t* __restrict__ wo_t,    // [128][128]
    const uint16_t* __restrict__ w1_t,    // [384][128] (rows>=344 zero)
    const uint16_t* __restrict__ w3_t,    // [384][128]
    const uint16_t* __restrict__ w2_t,    // [128][352] (k>=344 zero)
    float* __restrict__ out)              // [MROWS][128] fp32
{
  __shared__ __attribute__((aligned(16))) uint16_t h_l[16][136];
  __shared__ __attribute__((aligned(16))) uint16_t u_l[16][360];

  const int tid = threadIdx.x;
  const int w = tid >> 6, l = tid & 63;
  const int lg = l >> 4, lm = l & 15;
  const int R0 = blockIdx.x * 16;

  // ---- stage A: h = x + attn @ wo  (wave w -> col-tile w) ----
  short8 af[4];
  const uint16_t* Ap = attn_o + (size_t)(R0 + lm) * 128 + lg * 8;
#pragma unroll
  for (int ks = 0; ks < 4; ++ks) af[ks] = *(const short8*)(Ap + ks * 32);

  float hreg[4];
  {
    f32x4 acc = (f32x4){0.f, 0.f, 0.f, 0.f};
    const uint16_t* Bp = wo_t + (size_t)(w * 16 + lm) * 128 + lg * 8;
#pragma unroll
    for (int ks = 0; ks < 4; ++ks)
      acc = mfma32(af[ks], *(const short8*)(Bp + ks * 32), acc);
#pragma unroll
    for (int r = 0; r < 4; ++r) {
      const float h = acc[r] + x[(size_t)(R0 + lg * 4 + r) * 128 + w * 16 + lm];
      hreg[r] = h;
      h_l[lg * 4 + r][w * 16 + lm] = f2bf(h);
    }
  }
  __syncthreads();

  // ---- stage B: u = silu(h@w1) * (h@w3)  (wave w -> ct = w, w+8, w+16) ----
  short8 af2[4];
#pragma unroll
  for (int ks = 0; ks < 4; ++ks)
    af2[ks] = *(const short8*)&h_l[lm][ks * 32 + lg * 8];

#pragma unroll
  for (int j = 0; j < 3; ++j) {
    const int ct = w + j * 8;
    if (ct >= 22) break;
    f32x4 ag = (f32x4){0.f, 0.f, 0.f, 0.f};
    f32x4 ae = (f32x4){0.f, 0.f, 0.f, 0.f};
    const uint16_t* B1p = w1_t + (size_t)(ct * 16 + lm) * 128 + lg * 8;
    const uint16_t* B3p = w3_t + (size_t)(ct * 16 + lm) * 128 + lg * 8;
#pragma unroll
    for (int ks = 0; ks < 4; ++ks) {
      ag = mfma32(af2[ks], *(const short8*)(B1p + ks * 32), ag);
      ae = mfma32(af2[ks], *(const short8*)(B3p + ks * 32), ae);
    }
#pragma unroll
    for (int r = 0; r < 4; ++r) {
      const float g = ag[r];
      const float u = g / (1.f + __expf(-g)) * ae[r];
      u_l[lg * 4 + r][ct * 16 + lm] = f2bf(u);
    }
  }
  __syncthreads();

  // ---- stage C: out = h + u @ w2  (wave w -> col-tile w) ----
  {
    f32x4 acc = (f32x4){0.f, 0.f, 0.f, 0.f};
    const uint16_t* Bp = w2_t + (size_t)(w * 16 + lm) * HIDP + lg * 8;
#pragma unroll
    for (int k2 = 0; k2 < 11; ++k2) {
      const short8 a3 = *(const short8*)&u_l[lm][k2 * 32 + lg * 8];
      acc = mfma32(a3, *(const short8*)(Bp + k2 * 32), acc);
    }
#pragma unroll
    for (int r = 0; r < 4; ++r)
      out[(size_t)(R0 + lg * 4 + r) * 128 + w * 16 + lm] = hreg[r] + acc[r];
  }
}

// ------------------------------------------------------------------
extern "C" void kernel_launch(void* const* d_in, const int* in_sizes, int n_in,
                              void* d_out, int out_size, void* d_ws, size_t ws_size,
                              hipStream_t stream) {
  const float* x  = (const float*)d_in[0];
  const float* wq = (const float*)d_in[1];
  const float* wk = (const float*)d_in[2];
  const float* wv = (const float*)d_in[3];
  const float* wo = (const float*)d_in[4];
  const float* w1 = (const float*)d_in[5];
  const float* w3 = (const float*)d_in[6];
  const float* w2 = (const float*)d_in[7];
  float* out = (float*)d_out;

  char* ws = (char*)d_ws;
  size_t off = 0;
  auto alloc = [&](size_t bytes) {
    size_t o = off;
    off += (bytes + 255) & ~(size_t)255;
    return o;
  };
  uint16_t* qkv_t  = (uint16_t*)(ws + alloc(384 * 128 * 2));
  uint16_t* wo_t   = (uint16_t*)(ws + alloc(128 * 128 * 2));
  uint16_t* w1_t   = (uint16_t*)(ws + alloc(384 * 128 * 2));
  uint16_t* w3_t   = (uint16_t*)(ws + alloc(384 * 128 * 2));
  uint16_t* w2_t   = (uint16_t*)(ws + alloc(128 * HIDP * 2));
  uint16_t* q_buf  = (uint16_t*)(ws + alloc((size_t)MROWS * DIM * 2));
  uint16_t* kc_b   = (uint16_t*)(ws + alloc((size_t)MROWS * DIM * 2));
  uint16_t* vt_b   = (uint16_t*)(ws + alloc((size_t)MROWS * DIM * 2));
  uint16_t* attn_o = (uint16_t*)(ws + alloc((size_t)MROWS * DIM * 2));

  prep_kernel<<<512, 256, 0, stream>>>(wq, wk, wv, wo, w1, w3, w2,
                                       qkv_t, wo_t, w1_t, w3_t, w2_t);
  // qkv = x @ [wq*log2e | wk | wv] -> q_buf, Kc, Vt
  qkv_gemm<<<dim3(MROWS / 64, 6), 256, 0, stream>>>(
      x, qkv_t, q_buf, kc_b, vt_b);
  // flash attention: 2048 blocks (8/CU), 2-way key split
  attn_kernel<<<dim3(BATCH * NH * (SEQ / 64)), 256, 0, stream>>>(
      q_buf, kc_b, vt_b, attn_o);
  // fused: h = x + attn@wo; out = h + silu(h@w1)*(h@w3)@w2
  // 512 blocks x 512 threads, column-split waves
  ffn_kernel<<<dim3(MROWS / 16), 512, 0, stream>>>(
      attn_o, x, wo_t, w1_t, w3_t, w2_t, out);
}

// Round 11
// 72.261 us; speedup vs baseline: 1.4509x; 1.0793x over previous
//
#include <hip/hip_runtime.h>
#include <hip/hip_bf16.h>
#include <stdint.h>

typedef __attribute__((ext_vector_type(8))) short short8;
typedef __attribute__((ext_vector_type(4))) float f32x4;

#define NTHREADS 256
#define DIM 128
#define NH 16
#define HD 8
#define HIDDEN 344
#define HIDP 352          // HIDDEN padded to multiple of 32 (22 col-tiles)
#define BATCH 4
#define SEQ 2048
#define MROWS (BATCH * SEQ)   // 8192
#define LOG2E 1.4426950408889634f

static __device__ __forceinline__ uint16_t f2bf(float f) {
  union { float f; uint32_t u; } v; v.f = f;
  uint32_t r = v.u + 0x7FFFu + ((v.u >> 16) & 1u);
  return (uint16_t)(r >> 16);
}
static __device__ __forceinline__ float fast_exp2(float x) {
#if __has_builtin(__builtin_amdgcn_exp2f)
  return __builtin_amdgcn_exp2f(x);
#else
  return exp2f(x);
#endif
}
// RNE pack: compiler emits v_cvt_pk_bf16_f32
static __device__ __forceinline__ uint32_t pk2(float lo, float hi) {
  union { __hip_bfloat162 b; uint32_t u; } c;
  c.b = __float22bfloat162_rn(make_float2(lo, hi));
  return c.u;
}
// truncating bf16x2 pack: one v_perm_b32 (p >= 0, error <= 2^-8 relative)
static __device__ __forceinline__ uint32_t pkt(float lo, float hi) {
  return __builtin_amdgcn_perm(__builtin_bit_cast(uint32_t, hi),
                               __builtin_bit_cast(uint32_t, lo), 0x07060302u);
}
static __device__ __forceinline__ f32x4 mfma32(short8 a, short8 b, f32x4 c) {
  return __builtin_amdgcn_mfma_f32_16x16x32_bf16(a, b, c, 0, 0, 0);
}

// ------------------------------------------------------------------
// prep: weights -> transposed bf16 Wt[n][k], padded where needed.
// wq rows pre-scaled by log2(e) so attention uses exp2 directly.
// ------------------------------------------------------------------
__global__ __launch_bounds__(256) void prep_kernel(
    const float* __restrict__ wq,
    const float* __restrict__ wk, const float* __restrict__ wv,
    const float* __restrict__ wo, const float* __restrict__ w1,
    const float* __restrict__ w3, const float* __restrict__ w2,
    uint16_t* __restrict__ qkv_t,
    uint16_t* __restrict__ wo_t,  uint16_t* __restrict__ w1_t,
    uint16_t* __restrict__ w3_t,  uint16_t* __restrict__ w2_t)
{
  const int nt  = gridDim.x * blockDim.x;
  const int tid = blockIdx.x * blockDim.x + threadIdx.x;
  for (int i = tid; i < 384 * 128; i += nt) {
    int n = i >> 7, k = i & 127;
    const float* w = (n < 128) ? wq : ((n < 256) ? wk : wv);
    const float s = (n < 128) ? LOG2E : 1.0f;
    qkv_t[i] = f2bf(w[k * 128 + (n & 127)] * s);
  }
  for (int i = tid; i < 128 * 128; i += nt) {
    int n = i >> 7, k = i & 127;
    wo_t[i] = f2bf(wo[k * 128 + n]);
  }
  for (int i = tid; i < 384 * 128; i += nt) {
    int n = i >> 7, k = i & 127;
    w1_t[i] = (n < HIDDEN) ? f2bf(w1[k * HIDDEN + n]) : (uint16_t)0;
    w3_t[i] = (n < HIDDEN) ? f2bf(w3[k * HIDDEN + n]) : (uint16_t)0;
  }
  for (int i = tid; i < 128 * HIDP; i += nt) {
    int n = i / HIDP, k = i - n * HIDP;
    w2_t[i] = (k < HIDDEN) ? f2bf(w2[k * 128 + n]) : (uint16_t)0;
  }
}

// ------------------------------------------------------------------
// Register-streaming QKV GEMM (r7-proven): no LDS, no barriers.
// ------------------------------------------------------------------
__global__ __launch_bounds__(256, 4) void qkv_gemm(
    const float* __restrict__ Av, const uint16_t* __restrict__ B1t,
    uint16_t* __restrict__ outb,
    uint16_t* __restrict__ kc_o, uint16_t* __restrict__ vt_o)
{
  const int tid = threadIdx.x;
  const int w = tid >> 6, l = tid & 63;
  const int lg = l >> 4, lm = l & 15;
  const int row0 = blockIdx.x * 64 + w * 16;
  const int col0 = blockIdx.y * 64;

  short8 af[4];
  const float* Af = Av + (size_t)(row0 + lm) * 128 + lg * 8;
#pragma unroll
  for (int ks = 0; ks < 4; ++ks) {
    const f32x4 a0 = *(const f32x4*)(Af + ks * 32);
    const f32x4 a1 = *(const f32x4*)(Af + ks * 32 + 4);
    union { uint32_t u[4]; short8 s8; } cv;
    cv.u[0] = pk2(a0[0], a0[1]); cv.u[1] = pk2(a0[2], a0[3]);
    cv.u[2] = pk2(a1[0], a1[1]); cv.u[3] = pk2(a1[2], a1[3]);
    af[ks] = cv.s8;
  }

  f32x4 acc[4];
#pragma unroll
  for (int t = 0; t < 4; ++t) acc[t] = (f32x4){0.f, 0.f, 0.f, 0.f};

#pragma unroll
  for (int t = 0; t < 4; ++t) {
    const uint16_t* Bp = B1t + (size_t)(col0 + t * 16 + lm) * 128 + lg * 8;
#pragma unroll
    for (int ks = 0; ks < 4; ++ks)
      acc[t] = mfma32(af[ks], *(const short8*)(Bp + ks * 32), acc[t]);
  }

#pragma unroll
  for (int t = 0; t < 4; ++t) {
#pragma unroll
    for (int r = 0; r < 4; ++r) {
      const int row = row0 + lg * 4 + r;
      const int col = col0 + t * 16 + lm;
      const float v = acc[t][r];
      const int bb = row >> 11, ss = row & 2047;
      if (col < 128) {
        outb[(size_t)row * 128 + col] = f2bf(v);            // Q (pre-scaled)
      } else if (col < 256) {
        const int c = col - 128;
        kc_o[((size_t)((bb << 4) + (c >> 3)) * SEQ + ss) * 8 + (c & 7)] = f2bf(v);
      } else {
        const int c = col - 256;
        vt_o[((size_t)(bb * 128 + c)) * SEQ + ss] = f2bf(v);
      }
    }
  }
}

// ------------------------------------------------------------------
// Flash attention, 4 q-tiles/wave + 2-way key-split.
// Block = (b, h, 128 q rows); wave w: rows grp=(w>>1)*64 (4 tiles of
// 16), keys half kh=(w&1)*1024 (16 chunks of 64). ILP is the proven
// lever (r3->r5 1.77x; TLP r8->r10 0%): 64 independent exp2 per chunk.
// Tile-at-a-time processing keeps transient scores at 16 f32.
// QK^T swapped (mfma 16x16x32), permuted K rows so the QK D-layout IS
// the PV B-fragment layout. p = exp2(score), no max subtraction.
// PV A = Vt rows on lm; lm==8 ones-row -> acc row 8 = sum(p).
// No-max softmax => key-halves merge by pure addition via 16KB LDS.
// VGPR ~60 (2-tile) + ~25 -> fits (256,4)'s 128 cap with margin.
// ------------------------------------------------------------------
__global__ __launch_bounds__(256, 4) void attn_kernel(
    const uint16_t* __restrict__ qb,   // [MROWS][128]  (pre-scaled Q)
    const uint16_t* __restrict__ kc,   // [B*NH][SEQ][8]
    const uint16_t* __restrict__ vt,   // [B*NH*8][SEQ]
    uint16_t* __restrict__ attn_o)     // [MROWS][128]
{
  __shared__ __attribute__((aligned(16))) float part[4][64][16];

  const int tid = threadIdx.x;
  const int w = tid >> 6, l = tid & 63;
  const int lg = l >> 4, lm = l & 15;
  int bid = blockIdx.x;
  bid = (bid & 7) * 128 + (bid >> 3);   // bijective XCD swizzle (1024 % 8 == 0)
  const int qc = bid & 15;              // SEQ/128 = 16 q-chunks
  const int bh = bid >> 4;
  const int b = bh >> 4, h = bh & 15;
  const int grp = w >> 1, kh = w & 1;
  const int q0 = qc * 128 + grp * 64;

  const short8 zero8 = {0, 0, 0, 0, 0, 0, 0, 0};
  const f32x4 zero4 = {0.f, 0.f, 0.f, 0.f};
  const short ob = (short)0x3F80;  // bf16 1.0
  const short8 ones8 = {ob, ob, ob, ob, ob, ob, ob, ob};

  // Q fragments (4 tiles): B-frag lanes lg==0 hold Q[q][d=0..7]
  short8 qf[4];
#pragma unroll
  for (int t = 0; t < 4; ++t) {
    qf[t] = zero8;
    if (lg == 0)
      qf[t] = *(const short8*)(qb + (size_t)(b * SEQ + q0 + t * 16 + lm) * DIM + h * HD);
  }

  // wave covers keys [kh*1024, kh*1024+1024): 16 chunks of 64
  // permuted K base: tile-A row lm <- key 8*(lm>>2)+(lm&3)
  const uint16_t* kp = kc + (size_t)bh * SEQ * HD +
                       (kh * 1024 + 8 * (lm >> 2) + (lm & 3)) * HD;
  // V: A-frag lane (lg, lm<8) holds Vt[d=lm][key + 8*lg + j]
  const uint16_t* vp = vt + (size_t)(bh * HD + (lm & 7)) * SEQ + kh * 1024 + lg * 8;

  // named K/V double buffers
  short8 ka0 = zero8, ka1 = zero8, ka2 = zero8, ka3 = zero8;
  short8 kb0 = zero8, kb1 = zero8, kb2 = zero8, kb3 = zero8;
  const short8 vinit = (lm == 8) ? ones8 : zero8;
  short8 va0 = vinit, va1 = vinit, vb0 = vinit, vb1 = vinit;

  f32x4 acc[4];
#pragma unroll
  for (int t = 0; t < 4; ++t) acc[t] = zero4;

#define LK(R0, R1, R2, R3)                         \
  do { if (lg == 0) {                              \
    R0 = *(const short8*)(kp);                     \
    R1 = *(const short8*)(kp + 32);                \
    R2 = *(const short8*)(kp + 256);               \
    R3 = *(const short8*)(kp + 288); }             \
    kp += 512; } while (0)

#define LV(R0, R1)                                 \
  do { if (lm < HD) {                              \
    R0 = *(const short8*)(vp);                     \
    R1 = *(const short8*)(vp + 32); }              \
    vp += 64; } while (0)

#define PACKP(SA, SB, OUT)                                  \
  do { union { uint32_t u[4]; short8 s; } _t;               \
    _t.u[0] = pkt(fast_exp2(SA[0]), fast_exp2(SA[1]));      \
    _t.u[1] = pkt(fast_exp2(SA[2]), fast_exp2(SA[3]));      \
    _t.u[2] = pkt(fast_exp2(SB[0]), fast_exp2(SB[1]));      \
    _t.u[3] = pkt(fast_exp2(SB[2]), fast_exp2(SB[3]));      \
    OUT = _t.s; } while (0)

  // 4 q-tiles, tile-at-a-time (keeps transient s at 16 f32)
#define COMPUTE(K0, K1, K2, K3, V0, V1)                     \
  do {                                                      \
    _Pragma("unroll")                                       \
    for (int t = 0; t < 4; ++t) {                           \
      f32x4 s0, s1, s2, s3;                                 \
      __builtin_amdgcn_s_setprio(1);                        \
      s0 = mfma32(K0, qf[t], zero4);                        \
      s1 = mfma32(K1, qf[t], zero4);                        \
      s2 = mfma32(K2, qf[t], zero4);                        \
      s3 = mfma32(K3, qf[t], zero4);                        \
      __builtin_amdgcn_s_setprio(0);                        \
      short8 p0, p1;                                        \
      PACKP(s0, s1, p0);                                    \
      PACKP(s2, s3, p1);                                    \
      __builtin_amdgcn_s_setprio(1);                        \
      acc[t] = mfma32(V0, p0, acc[t]);                      \
      acc[t] = mfma32(V1, p1, acc[t]);                      \
      __builtin_amdgcn_s_setprio(0);                        \
    }                                                       \
  } while (0)

  // software pipeline: 16 chunks of 64 keys; load i+1 before compute i
  LK(ka0, ka1, ka2, ka3); LV(va0, va1);
#pragma unroll 1
  for (int it = 0; it < 7; ++it) {
    LK(kb0, kb1, kb2, kb3); LV(vb0, vb1);
    COMPUTE(ka0, ka1, ka2, ka3, va0, va1);
    LK(ka0, ka1, ka2, ka3); LV(va0, va1);
    COMPUTE(kb0, kb1, kb2, kb3, vb0, vb1);
  }
  LK(kb0, kb1, kb2, kb3); LV(vb0, vb1);
  COMPUTE(ka0, ka1, ka2, ka3, va0, va1);
  COMPUTE(kb0, kb1, kb2, kb3, vb0, vb1);

#undef LK
#undef LV
#undef PACKP
#undef COMPUTE

  // ---- merge the two key-halves (pure addition; no-max softmax) ----
#pragma unroll
  for (int t = 0; t < 4; ++t) *(f32x4*)&part[w][l][t * 4] = acc[t];
  __syncthreads();

  if (kh == 0) {   // waves 0 (grp0) and 2 (grp1) merge + write
#pragma unroll
    for (int t = 0; t < 4; ++t) {
      const f32x4 m = *(const f32x4*)&part[w][l][t * 4] +
                      *(const f32x4*)&part[w + 1][l][t * 4];
      // row 8 (lane 32+lm, reg 0) holds sum(p) for q=lm
      const float inv = 1.0f / __shfl(m[0], 32 + lm);
      if (lg < 2) {
        const size_t o = (size_t)(b * SEQ + q0 + t * 16 + lm) * DIM + h * HD + lg * 4;
        *(uint32_t*)(attn_o + o)     = pk2(m[0] * inv, m[1] * inv);
        *(uint32_t*)(attn_o + o + 2) = pk2(m[2] * inv, m[3] * inv);
      }
    }
  }
}

// ------------------------------------------------------------------
// Fused post-attention chain, column-split (r10-proven).
// Block = 16 rows x 8 waves (512 thr); grid = 512 blocks.
// ------------------------------------------------------------------
__global__ __launch_bounds__(512) void ffn_kernel(
    const uint16_t* __restrict__ attn_o,  // [MROWS][128] bf16
    const float* __restrict__ x,          // [MROWS][128] fp32
    const uint16_t* __restrict__ wo_t,    // [128][128]
    const uint16_t* __restrict__ w1_t,    // [384][128] (rows>=344 zero)
    const uint16_t* __restrict__ w3_t,    // [384][128]
    const uint16_t* __restrict__ w2_t,    // [128][352] (k>=344 zero)
    float* __restrict__ out)              // [MROWS][128] fp32
{
  __shared__ __attribute__((aligned(16))) uint16_t h_l[16][136];
  __shared__ __attribute__((aligned(16))) uint16_t u_l[16][360];

  const int tid = threadIdx.x;
  const int w = tid >> 6, l = tid & 63;
  const int lg = l >> 4, lm = l & 15;
  const int R0 = blockIdx.x * 16;

  // ---- stage A: h = x + attn @ wo  (wave w -> col-tile w) ----
  short8 af[4];
  const uint16_t* Ap = attn_o + (size_t)(R0 + lm) * 128 + lg * 8;
#pragma unroll
  for (int ks = 0; ks < 4; ++ks) af[ks] = *(const short8*)(Ap + ks * 32);

  float hreg[4];
  {
    f32x4 acc = (f32x4){0.f, 0.f, 0.f, 0.f};
    const uint16_t* Bp = wo_t + (size_t)(w * 16 + lm) * 128 + lg * 8;
#pragma unroll
    for (int ks = 0; ks < 4; ++ks)
      acc = mfma32(af[ks], *(const short8*)(Bp + ks * 32), acc);
#pragma unroll
    for (int r = 0; r < 4; ++r) {
      const float h = acc[r] + x[(size_t)(R0 + lg * 4 + r) * 128 + w * 16 + lm];
      hreg[r] = h;
      h_l[lg * 4 + r][w * 16 + lm] = f2bf(h);
    }
  }
  __syncthreads();

  // ---- stage B: u = silu(h@w1) * (h@w3)  (wave w -> ct = w, w+8, w+16) ----
  short8 af2[4];
#pragma unroll
  for (int ks = 0; ks < 4; ++ks)
    af2[ks] = *(const short8*)&h_l[lm][ks * 32 + lg * 8];

#pragma unroll
  for (int j = 0; j < 3; ++j) {
    const int ct = w + j * 8;
    if (ct >= 22) break;
    f32x4 ag = (f32x4){0.f, 0.f, 0.f, 0.f};
    f32x4 ae = (f32x4){0.f, 0.f, 0.f, 0.f};
    const uint16_t* B1p = w1_t + (size_t)(ct * 16 + lm) * 128 + lg * 8;
    const uint16_t* B3p = w3_t + (size_t)(ct * 16 + lm) * 128 + lg * 8;
#pragma unroll
    for (int ks = 0; ks < 4; ++ks) {
      ag = mfma32(af2[ks], *(const short8*)(B1p + ks * 32), ag);
      ae = mfma32(af2[ks], *(const short8*)(B3p + ks * 32), ae);
    }
#pragma unroll
    for (int r = 0; r < 4; ++r) {
      const float g = ag[r];
      const float u = g / (1.f + __expf(-g)) * ae[r];
      u_l[lg * 4 + r][ct * 16 + lm] = f2bf(u);
    }
  }
  __syncthreads();

  // ---- stage C: out = h + u @ w2  (wave w -> col-tile w) ----
  {
    f32x4 acc = (f32x4){0.f, 0.f, 0.f, 0.f};
    const uint16_t* Bp = w2_t + (size_t)(w * 16 + lm) * HIDP + lg * 8;
#pragma unroll
    for (int k2 = 0; k2 < 11; ++k2) {
      const short8 a3 = *(const short8*)&u_l[lm][k2 * 32 + lg * 8];
      acc = mfma32(a3, *(const short8*)(Bp + k2 * 32), acc);
    }
#pragma unroll
    for (int r = 0; r < 4; ++r)
      out[(size_t)(R0 + lg * 4 + r) * 128 + w * 16 + lm] = hreg[r] + acc[r];
  }
}

// ------------------------------------------------------------------
extern "C" void kernel_launch(void* const* d_in, const int* in_sizes, int n_in,
                              void* d_out, int out_size, void* d_ws, size_t ws_size,
                              hipStream_t stream) {
  const float* x  = (const float*)d_in[0];
  const float* wq = (const float*)d_in[1];
  const float* wk = (const float*)d_in[2];
  const float* wv = (const float*)d_in[3];
  const float* wo = (const float*)d_in[4];
  const float* w1 = (const float*)d_in[5];
  const float* w3 = (const float*)d_in[6];
  const float* w2 = (const float*)d_in[7];
  float* out = (float*)d_out;

  char* ws = (char*)d_ws;
  size_t off = 0;
  auto alloc = [&](size_t bytes) {
    size_t o = off;
    off += (bytes + 255) & ~(size_t)255;
    return o;
  };
  uint16_t* qkv_t  = (uint16_t*)(ws + alloc(384 * 128 * 2));
  uint16_t* wo_t   = (uint16_t*)(ws + alloc(128 * 128 * 2));
  uint16_t* w1_t   = (uint16_t*)(ws + alloc(384 * 128 * 2));
  uint16_t* w3_t   = (uint16_t*)(ws + alloc(384 * 128 * 2));
  uint16_t* w2_t   = (uint16_t*)(ws + alloc(128 * HIDP * 2));
  uint16_t* q_buf  = (uint16_t*)(ws + alloc((size_t)MROWS * DIM * 2));
  uint16_t* kc_b   = (uint16_t*)(ws + alloc((size_t)MROWS * DIM * 2));
  uint16_t* vt_b   = (uint16_t*)(ws + alloc((size_t)MROWS * DIM * 2));
  uint16_t* attn_o = (uint16_t*)(ws + alloc((size_t)MROWS * DIM * 2));

  prep_kernel<<<512, 256, 0, stream>>>(wq, wk, wv, wo, w1, w3, w2,
                                       qkv_t, wo_t, w1_t, w3_t, w2_t);
  // qkv = x @ [wq*log2e | wk | wv] -> q_buf, Kc, Vt
  qkv_gemm<<<dim3(MROWS / 64, 6), 256, 0, stream>>>(
      x, qkv_t, q_buf, kc_b, vt_b);
  // flash attention: 1024 blocks, 4 q-tiles/wave, 2-way key split
  attn_kernel<<<dim3(BATCH * NH * (SEQ / 128)), 256, 0, stream>>>(
      q_buf, kc_b, vt_b, attn_o);
  // fused: h = x + attn@wo; out = h + silu(h@w1)*(h@w3)@w2
  ffn_kernel<<<dim3(MROWS / 16), 512, 0, stream>>>(
      attn_o, x, wo_t, w1_t, w3_t, w2_t, out);
}

// Round 12
// 71.286 us; speedup vs baseline: 1.4708x; 1.0137x over previous
//
#include <hip/hip_runtime.h>
#include <hip/hip_bf16.h>
#include <stdint.h>

typedef __attribute__((ext_vector_type(8))) short short8;
typedef __attribute__((ext_vector_type(4))) float f32x4;

#define NTHREADS 256
#define DIM 128
#define NH 16
#define HD 8
#define HIDDEN 344
#define HIDP 352          // HIDDEN padded to multiple of 32 (22 col-tiles)
#define BATCH 4
#define SEQ 2048
#define MROWS (BATCH * SEQ)   // 8192
#define LOG2E 1.4426950408889634f

static __device__ __forceinline__ uint16_t f2bf(float f) {
  union { float f; uint32_t u; } v; v.f = f;
  uint32_t r = v.u + 0x7FFFu + ((v.u >> 16) & 1u);
  return (uint16_t)(r >> 16);
}
static __device__ __forceinline__ float fast_exp2(float x) {
#if __has_builtin(__builtin_amdgcn_exp2f)
  return __builtin_amdgcn_exp2f(x);
#else
  return exp2f(x);
#endif
}
// RNE pack: compiler emits v_cvt_pk_bf16_f32
static __device__ __forceinline__ uint32_t pk2(float lo, float hi) {
  union { __hip_bfloat162 b; uint32_t u; } c;
  c.b = __float22bfloat162_rn(make_float2(lo, hi));
  return c.u;
}
// truncating bf16x2 pack: one v_perm_b32 (p >= 0, error <= 2^-8 relative)
static __device__ __forceinline__ uint32_t pkt(float lo, float hi) {
  return __builtin_amdgcn_perm(__builtin_bit_cast(uint32_t, hi),
                               __builtin_bit_cast(uint32_t, lo), 0x07060302u);
}
static __device__ __forceinline__ f32x4 mfma32(short8 a, short8 b, f32x4 c) {
  return __builtin_amdgcn_mfma_f32_16x16x32_bf16(a, b, c, 0, 0, 0);
}

// ------------------------------------------------------------------
// prep: weights -> transposed bf16 Wt[n][k], padded where needed.
// wq rows pre-scaled by log2(e) so attention uses exp2 directly.
// ------------------------------------------------------------------
__global__ __launch_bounds__(256) void prep_kernel(
    const float* __restrict__ wq,
    const float* __restrict__ wk, const float* __restrict__ wv,
    const float* __restrict__ wo, const float* __restrict__ w1,
    const float* __restrict__ w3, const float* __restrict__ w2,
    uint16_t* __restrict__ qkv_t,
    uint16_t* __restrict__ wo_t,  uint16_t* __restrict__ w1_t,
    uint16_t* __restrict__ w3_t,  uint16_t* __restrict__ w2_t)
{
  const int nt  = gridDim.x * blockDim.x;
  const int tid = blockIdx.x * blockDim.x + threadIdx.x;
  for (int i = tid; i < 384 * 128; i += nt) {
    int n = i >> 7, k = i & 127;
    const float* w = (n < 128) ? wq : ((n < 256) ? wk : wv);
    const float s = (n < 128) ? LOG2E : 1.0f;
    qkv_t[i] = f2bf(w[k * 128 + (n & 127)] * s);
  }
  for (int i = tid; i < 128 * 128; i += nt) {
    int n = i >> 7, k = i & 127;
    wo_t[i] = f2bf(wo[k * 128 + n]);
  }
  for (int i = tid; i < 384 * 128; i += nt) {
    int n = i >> 7, k = i & 127;
    w1_t[i] = (n < HIDDEN) ? f2bf(w1[k * HIDDEN + n]) : (uint16_t)0;
    w3_t[i] = (n < HIDDEN) ? f2bf(w3[k * HIDDEN + n]) : (uint16_t)0;
  }
  for (int i = tid; i < 128 * HIDP; i += nt) {
    int n = i / HIDP, k = i - n * HIDP;
    w2_t[i] = (k < HIDDEN) ? f2bf(w2[k * 128 + n]) : (uint16_t)0;
  }
}

// ------------------------------------------------------------------
// Register-streaming QKV GEMM (r7-proven): no LDS, no barriers.
// ------------------------------------------------------------------
__global__ __launch_bounds__(256, 4) void qkv_gemm(
    const float* __restrict__ Av, const uint16_t* __restrict__ B1t,
    uint16_t* __restrict__ outb,
    uint16_t* __restrict__ kc_o, uint16_t* __restrict__ vt_o)
{
  const int tid = threadIdx.x;
  const int w = tid >> 6, l = tid & 63;
  const int lg = l >> 4, lm = l & 15;
  const int row0 = blockIdx.x * 64 + w * 16;
  const int col0 = blockIdx.y * 64;

  short8 af[4];
  const float* Af = Av + (size_t)(row0 + lm) * 128 + lg * 8;
#pragma unroll
  for (int ks = 0; ks < 4; ++ks) {
    const f32x4 a0 = *(const f32x4*)(Af + ks * 32);
    const f32x4 a1 = *(const f32x4*)(Af + ks * 32 + 4);
    union { uint32_t u[4]; short8 s8; } cv;
    cv.u[0] = pk2(a0[0], a0[1]); cv.u[1] = pk2(a0[2], a0[3]);
    cv.u[2] = pk2(a1[0], a1[1]); cv.u[3] = pk2(a1[2], a1[3]);
    af[ks] = cv.s8;
  }

  f32x4 acc[4];
#pragma unroll
  for (int t = 0; t < 4; ++t) acc[t] = (f32x4){0.f, 0.f, 0.f, 0.f};

#pragma unroll
  for (int t = 0; t < 4; ++t) {
    const uint16_t* Bp = B1t + (size_t)(col0 + t * 16 + lm) * 128 + lg * 8;
#pragma unroll
    for (int ks = 0; ks < 4; ++ks)
      acc[t] = mfma32(af[ks], *(const short8*)(Bp + ks * 32), acc[t]);
  }

#pragma unroll
  for (int t = 0; t < 4; ++t) {
#pragma unroll
    for (int r = 0; r < 4; ++r) {
      const int row = row0 + lg * 4 + r;
      const int col = col0 + t * 16 + lm;
      const float v = acc[t][r];
      const int bb = row >> 11, ss = row & 2047;
      if (col < 128) {
        outb[(size_t)row * 128 + col] = f2bf(v);            // Q (pre-scaled)
      } else if (col < 256) {
        const int c = col - 128;
        kc_o[((size_t)((bb << 4) + (c >> 3)) * SEQ + ss) * 8 + (c & 7)] = f2bf(v);
      } else {
        const int c = col - 256;
        vt_o[((size_t)(bb * 128 + c)) * SEQ + ss] = f2bf(v);
      }
    }
  }
}

// ------------------------------------------------------------------
// Flash attention, 4 q-tiles/wave + 4-WAY key-split.
// Block = (b, h, 64 q rows); ALL 4 waves compute the same 4 q-tiles,
// each over a different key QUARTER (kh = w, 8 chunks of 64 keys).
// Grid 2048 = 8 blocks/CU potential -> occupancy VGPR-capped (~5/SIMD)
// instead of grid-capped at 4 (r11). Per-wave ILP unchanged (the
// proven lever); per-wave chain halves to 8 chunks.
// QK^T swapped (mfma 16x16x32), permuted K rows so the QK D-layout IS
// the PV B-fragment layout. p = exp2(score), no max subtraction.
// PV A = Vt rows on lm; lm==8 ones-row -> acc row 8 = sum(p).
// No-max softmax => key-quarters merge by pure addition via 16KB LDS;
// wave t merges tile t (parallel merge, 1 barrier).
// Tail prefetch reads past the key range into adjacent ws allocations
// (read-only, unused). Do NOT tighten launch_bounds (r6/r7 lesson).
// ------------------------------------------------------------------
__global__ __launch_bounds__(256, 4) void attn_kernel(
    const uint16_t* __restrict__ qb,   // [MROWS][128]  (pre-scaled Q)
    const uint16_t* __restrict__ kc,   // [B*NH][SEQ][8]
    const uint16_t* __restrict__ vt,   // [B*NH*8][SEQ]
    uint16_t* __restrict__ attn_o)     // [MROWS][128]
{
  __shared__ __attribute__((aligned(16))) float part[4][64][16];

  const int tid = threadIdx.x;
  const int w = tid >> 6, l = tid & 63;
  const int lg = l >> 4, lm = l & 15;
  int bid = blockIdx.x;
  bid = (bid & 7) * 256 + (bid >> 3);   // bijective XCD swizzle (2048 % 8 == 0)
  const int qc = bid & 31;              // SEQ/64 = 32 q-chunks
  const int bh = bid >> 5;
  const int b = bh >> 4, h = bh & 15;
  const int q0 = qc * 64;
  const int kh = w;                     // key quarter per wave

  const short8 zero8 = {0, 0, 0, 0, 0, 0, 0, 0};
  const f32x4 zero4 = {0.f, 0.f, 0.f, 0.f};
  const short ob = (short)0x3F80;  // bf16 1.0
  const short8 ones8 = {ob, ob, ob, ob, ob, ob, ob, ob};

  // Q fragments (4 tiles, same rows for all waves): lg==0 holds Q[q][d]
  short8 qf[4];
#pragma unroll
  for (int t = 0; t < 4; ++t) {
    qf[t] = zero8;
    if (lg == 0)
      qf[t] = *(const short8*)(qb + (size_t)(b * SEQ + q0 + t * 16 + lm) * DIM + h * HD);
  }

  // wave covers keys [kh*512, kh*512+512): 8 chunks of 64
  // permuted K base: tile-A row lm <- key 8*(lm>>2)+(lm&3)
  const uint16_t* kp = kc + (size_t)bh * SEQ * HD +
                       (kh * 512 + 8 * (lm >> 2) + (lm & 3)) * HD;
  // V: A-frag lane (lg, lm<8) holds Vt[d=lm][key + 8*lg + j]
  const uint16_t* vp = vt + (size_t)(bh * HD + (lm & 7)) * SEQ + kh * 512 + lg * 8;

  // named K/V double buffers
  short8 ka0 = zero8, ka1 = zero8, ka2 = zero8, ka3 = zero8;
  short8 kb0 = zero8, kb1 = zero8, kb2 = zero8, kb3 = zero8;
  const short8 vinit = (lm == 8) ? ones8 : zero8;
  short8 va0 = vinit, va1 = vinit, vb0 = vinit, vb1 = vinit;

  f32x4 acc[4];
#pragma unroll
  for (int t = 0; t < 4; ++t) acc[t] = zero4;

#define LK(R0, R1, R2, R3)                         \
  do { if (lg == 0) {                              \
    R0 = *(const short8*)(kp);                     \
    R1 = *(const short8*)(kp + 32);                \
    R2 = *(const short8*)(kp + 256);               \
    R3 = *(const short8*)(kp + 288); }             \
    kp += 512; } while (0)

#define LV(R0, R1)                                 \
  do { if (lm < HD) {                              \
    R0 = *(const short8*)(vp);                     \
    R1 = *(const short8*)(vp + 32); }              \
    vp += 64; } while (0)

#define PACKP(SA, SB, OUT)                                  \
  do { union { uint32_t u[4]; short8 s; } _t;               \
    _t.u[0] = pkt(fast_exp2(SA[0]), fast_exp2(SA[1]));      \
    _t.u[1] = pkt(fast_exp2(SA[2]), fast_exp2(SA[3]));      \
    _t.u[2] = pkt(fast_exp2(SB[0]), fast_exp2(SB[1]));      \
    _t.u[3] = pkt(fast_exp2(SB[2]), fast_exp2(SB[3]));      \
    OUT = _t.s; } while (0)

  // 4 q-tiles, tile-at-a-time (keeps transient s at 16 f32)
#define COMPUTE(K0, K1, K2, K3, V0, V1)                     \
  do {                                                      \
    _Pragma("unroll")                                       \
    for (int t = 0; t < 4; ++t) {                           \
      f32x4 s0, s1, s2, s3;                                 \
      __builtin_amdgcn_s_setprio(1);                        \
      s0 = mfma32(K0, qf[t], zero4);                        \
      s1 = mfma32(K1, qf[t], zero4);                        \
      s2 = mfma32(K2, qf[t], zero4);                        \
      s3 = mfma32(K3, qf[t], zero4);                        \
      __builtin_amdgcn_s_setprio(0);                        \
      short8 p0, p1;                                        \
      PACKP(s0, s1, p0);                                    \
      PACKP(s2, s3, p1);                                    \
      __builtin_amdgcn_s_setprio(1);                        \
      acc[t] = mfma32(V0, p0, acc[t]);                      \
      acc[t] = mfma32(V1, p1, acc[t]);                      \
      __builtin_amdgcn_s_setprio(0);                        \
    }                                                       \
  } while (0)

  // software pipeline: 8 chunks of 64 keys; load i+1 before compute i
  LK(ka0, ka1, ka2, ka3); LV(va0, va1);
#pragma unroll 1
  for (int it = 0; it < 3; ++it) {
    LK(kb0, kb1, kb2, kb3); LV(vb0, vb1);
    COMPUTE(ka0, ka1, ka2, ka3, va0, va1);
    LK(ka0, ka1, ka2, ka3); LV(va0, va1);
    COMPUTE(kb0, kb1, kb2, kb3, vb0, vb1);
  }
  LK(kb0, kb1, kb2, kb3); LV(vb0, vb1);
  COMPUTE(ka0, ka1, ka2, ka3, va0, va1);
  COMPUTE(kb0, kb1, kb2, kb3, vb0, vb1);

#undef LK
#undef LV
#undef PACKP
#undef COMPUTE

  // ---- merge the four key-quarters (pure addition; no-max softmax) ----
#pragma unroll
  for (int t = 0; t < 4; ++t) *(f32x4*)&part[w][l][t * 4] = acc[t];
  __syncthreads();

  // wave w merges tile w across the 4 key-quarters
  {
    const f32x4 m = (*(const f32x4*)&part[0][l][w * 4] +
                     *(const f32x4*)&part[1][l][w * 4]) +
                    (*(const f32x4*)&part[2][l][w * 4] +
                     *(const f32x4*)&part[3][l][w * 4]);
    // row 8 (lane 32+lm, reg 0) holds sum(p) for q=lm
    const float inv = 1.0f / __shfl(m[0], 32 + lm);
    if (lg < 2) {
      const size_t o = (size_t)(b * SEQ + q0 + w * 16 + lm) * DIM + h * HD + lg * 4;
      *(uint32_t*)(attn_o + o)     = pk2(m[0] * inv, m[1] * inv);
      *(uint32_t*)(attn_o + o + 2) = pk2(m[2] * inv, m[3] * inv);
    }
  }
}

// ------------------------------------------------------------------
// Fused post-attention chain, column-split (r10-proven).
// Block = 16 rows x 8 waves (512 thr); grid = 512 blocks.
// ------------------------------------------------------------------
__global__ __launch_bounds__(512) void ffn_kernel(
    const uint16_t* __restrict__ attn_o,  // [MROWS][128] bf16
    const float* __restrict__ x,          // [MROWS][128] fp32
    const uint16_t* __restrict__ wo_t,    // [128][128]
    const uint16_t* __restrict__ w1_t,    // [384][128] (rows>=344 zero)
    const uint16_t* __restrict__ w3_t,    // [384][128]
    const uint16_t* __restrict__ w2_t,    // [128][352] (k>=344 zero)
    float* __restrict__ out)              // [MROWS][128] fp32
{
  __shared__ __attribute__((aligned(16))) uint16_t h_l[16][136];
  __shared__ __attribute__((aligned(16))) uint16_t u_l[16][360];

  const int tid = threadIdx.x;
  const int w = tid >> 6, l = tid & 63;
  const int lg = l >> 4, lm = l & 15;
  const int R0 = blockIdx.x * 16;

  // ---- stage A: h = x + attn @ wo  (wave w -> col-tile w) ----
  short8 af[4];
  const uint16_t* Ap = attn_o + (size_t)(R0 + lm) * 128 + lg * 8;
#pragma unroll
  for (int ks = 0; ks < 4; ++ks) af[ks] = *(const short8*)(Ap + ks * 32);

  float hreg[4];
  {
    f32x4 acc = (f32x4){0.f, 0.f, 0.f, 0.f};
    const uint16_t* Bp = wo_t + (size_t)(w * 16 + lm) * 128 + lg * 8;
#pragma unroll
    for (int ks = 0; ks < 4; ++ks)
      acc = mfma32(af[ks], *(const short8*)(Bp + ks * 32), acc);
#pragma unroll
    for (int r = 0; r < 4; ++r) {
      const float h = acc[r] + x[(size_t)(R0 + lg * 4 + r) * 128 + w * 16 + lm];
      hreg[r] = h;
      h_l[lg * 4 + r][w * 16 + lm] = f2bf(h);
    }
  }
  __syncthreads();

  // ---- stage B: u = silu(h@w1) * (h@w3)  (wave w -> ct = w, w+8, w+16) ----
  short8 af2[4];
#pragma unroll
  for (int ks = 0; ks < 4; ++ks)
    af2[ks] = *(const short8*)&h_l[lm][ks * 32 + lg * 8];

#pragma unroll
  for (int j = 0; j < 3; ++j) {
    const int ct = w + j * 8;
    if (ct >= 22) break;
    f32x4 ag = (f32x4){0.f, 0.f, 0.f, 0.f};
    f32x4 ae = (f32x4){0.f, 0.f, 0.f, 0.f};
    const uint16_t* B1p = w1_t + (size_t)(ct * 16 + lm) * 128 + lg * 8;
    const uint16_t* B3p = w3_t + (size_t)(ct * 16 + lm) * 128 + lg * 8;
#pragma unroll
    for (int ks = 0; ks < 4; ++ks) {
      ag = mfma32(af2[ks], *(const short8*)(B1p + ks * 32), ag);
      ae = mfma32(af2[ks], *(const short8*)(B3p + ks * 32), ae);
    }
#pragma unroll
    for (int r = 0; r < 4; ++r) {
      const float g = ag[r];
      const float u = g / (1.f + __expf(-g)) * ae[r];
      u_l[lg * 4 + r][ct * 16 + lm] = f2bf(u);
    }
  }
  __syncthreads();

  // ---- stage C: out = h + u @ w2  (wave w -> col-tile w) ----
  {
    f32x4 acc = (f32x4){0.f, 0.f, 0.f, 0.f};
    const uint16_t* Bp = w2_t + (size_t)(w * 16 + lm) * HIDP + lg * 8;
#pragma unroll
    for (int k2 = 0; k2 < 11; ++k2) {
      const short8 a3 = *(const short8*)&u_l[lm][k2 * 32 + lg * 8];
      acc = mfma32(a3, *(const short8*)(Bp + k2 * 32), acc);
    }
#pragma unroll
    for (int r = 0; r < 4; ++r)
      out[(size_t)(R0 + lg * 4 + r) * 128 + w * 16 + lm] = hreg[r] + acc[r];
  }
}

// ------------------------------------------------------------------
extern "C" void kernel_launch(void* const* d_in, const int* in_sizes, int n_in,
                              void* d_out, int out_size, void* d_ws, size_t ws_size,
                              hipStream_t stream) {
  const float* x  = (const float*)d_in[0];
  const float* wq = (const float*)d_in[1];
  const float* wk = (const float*)d_in[2];
  const float* wv = (const float*)d_in[3];
  const float* wo = (const float*)d_in[4];
  const float* w1 = (const float*)d_in[5];
  const float* w3 = (const float*)d_in[6];
  const float* w2 = (const float*)d_in[7];
  float* out = (float*)d_out;

  char* ws = (char*)d_ws;
  size_t off = 0;
  auto alloc = [&](size_t bytes) {
    size_t o = off;
    off += (bytes + 255) & ~(size_t)255;
    return o;
  };
  uint16_t* qkv_t  = (uint16_t*)(ws + alloc(384 * 128 * 2));
  uint16_t* wo_t   = (uint16_t*)(ws + alloc(128 * 128 * 2));
  uint16_t* w1_t   = (uint16_t*)(ws + alloc(384 * 128 * 2));
  uint16_t* w3_t   = (uint16_t*)(ws + alloc(384 * 128 * 2));
  uint16_t* w2_t   = (uint16_t*)(ws + alloc(128 * HIDP * 2));
  uint16_t* q_buf  = (uint16_t*)(ws + alloc((size_t)MROWS * DIM * 2));
  uint16_t* kc_b   = (uint16_t*)(ws + alloc((size_t)MROWS * DIM * 2));
  uint16_t* vt_b   = (uint16_t*)(ws + alloc((size_t)MROWS * DIM * 2));
  uint16_t* attn_o = (uint16_t*)(ws + alloc((size_t)MROWS * DIM * 2));

  prep_kernel<<<512, 256, 0, stream>>>(wq, wk, wv, wo, w1, w3, w2,
                                       qkv_t, wo_t, w1_t, w3_t, w2_t);
  // qkv = x @ [wq*log2e | wk | wv] -> q_buf, Kc, Vt
  qkv_gemm<<<dim3(MROWS / 64, 6), 256, 0, stream>>>(
      x, qkv_t, q_buf, kc_b, vt_b);
  // flash attention: 2048 blocks, 4 q-tiles/wave, 4-way key split
  attn_kernel<<<dim3(BATCH * NH * (SEQ / 64)), 256, 0, stream>>>(
      q_buf, kc_b, vt_b, attn_o);
  // fused: h = x + attn@wo; out = h + silu(h@w1)*(h@w3)@w2
  ffn_kernel<<<dim3(MROWS / 16), 512, 0, stream>>>(
      attn_o, x, wo_t, w1_t, w3_t, w2_t, out);
}

// Round 13
// 71.027 us; speedup vs baseline: 1.4761x; 1.0036x over previous
//
#include <hip/hip_runtime.h>
#include <hip/hip_bf16.h>
#include <stdint.h>

typedef __attribute__((ext_vector_type(8))) short short8;
typedef __attribute__((ext_vector_type(4))) float f32x4;

#define NTHREADS 256
#define DIM 128
#define NH 16
#define HD 8
#define HIDDEN 344
#define HIDP 352          // HIDDEN padded to multiple of 32 (22 col-tiles)
#define BATCH 4
#define SEQ 2048
#define MROWS (BATCH * SEQ)   // 8192
#define LOG2E 1.4426950408889634f

static __device__ __forceinline__ uint16_t f2bf(float f) {
  union { float f; uint32_t u; } v; v.f = f;
  uint32_t r = v.u + 0x7FFFu + ((v.u >> 16) & 1u);
  return (uint16_t)(r >> 16);
}
static __device__ __forceinline__ float fast_exp2(float x) {
#if __has_builtin(__builtin_amdgcn_exp2f)
  return __builtin_amdgcn_exp2f(x);
#else
  return exp2f(x);
#endif
}
// RNE pack: compiler emits v_cvt_pk_bf16_f32
static __device__ __forceinline__ uint32_t pk2(float lo, float hi) {
  union { __hip_bfloat162 b; uint32_t u; } c;
  c.b = __float22bfloat162_rn(make_float2(lo, hi));
  return c.u;
}
// truncating bf16x2 pack: one v_perm_b32 (p >= 0, error <= 2^-8 relative)
static __device__ __forceinline__ uint32_t pkt(float lo, float hi) {
  return __builtin_amdgcn_perm(__builtin_bit_cast(uint32_t, hi),
                               __builtin_bit_cast(uint32_t, lo), 0x07060302u);
}
static __device__ __forceinline__ f32x4 mfma32(short8 a, short8 b, f32x4 c) {
  return __builtin_amdgcn_mfma_f32_16x16x32_bf16(a, b, c, 0, 0, 0);
}

// ------------------------------------------------------------------
// prep: weights -> transposed bf16 Wt[n][k], padded where needed.
// wq rows pre-scaled by log2(e) so attention uses exp2 directly.
// ------------------------------------------------------------------
__global__ __launch_bounds__(256) void prep_kernel(
    const float* __restrict__ wq,
    const float* __restrict__ wk, const float* __restrict__ wv,
    const float* __restrict__ wo, const float* __restrict__ w1,
    const float* __restrict__ w3, const float* __restrict__ w2,
    uint16_t* __restrict__ qkv_t,
    uint16_t* __restrict__ wo_t,  uint16_t* __restrict__ w1_t,
    uint16_t* __restrict__ w3_t,  uint16_t* __restrict__ w2_t)
{
  const int nt  = gridDim.x * blockDim.x;
  const int tid = blockIdx.x * blockDim.x + threadIdx.x;
  for (int i = tid; i < 384 * 128; i += nt) {
    int n = i >> 7, k = i & 127;
    const float* w = (n < 128) ? wq : ((n < 256) ? wk : wv);
    const float s = (n < 128) ? LOG2E : 1.0f;
    qkv_t[i] = f2bf(w[k * 128 + (n & 127)] * s);
  }
  for (int i = tid; i < 128 * 128; i += nt) {
    int n = i >> 7, k = i & 127;
    wo_t[i] = f2bf(wo[k * 128 + n]);
  }
  for (int i = tid; i < 384 * 128; i += nt) {
    int n = i >> 7, k = i & 127;
    w1_t[i] = (n < HIDDEN) ? f2bf(w1[k * HIDDEN + n]) : (uint16_t)0;
    w3_t[i] = (n < HIDDEN) ? f2bf(w3[k * HIDDEN + n]) : (uint16_t)0;
  }
  for (int i = tid; i < 128 * HIDP; i += nt) {
    int n = i / HIDP, k = i - n * HIDP;
    w2_t[i] = (k < HIDDEN) ? f2bf(w2[k * 128 + n]) : (uint16_t)0;
  }
}

// ------------------------------------------------------------------
// Register-streaming QKV GEMM (r7-proven): no LDS, no barriers.
// ------------------------------------------------------------------
__global__ __launch_bounds__(256, 4) void qkv_gemm(
    const float* __restrict__ Av, const uint16_t* __restrict__ B1t,
    uint16_t* __restrict__ outb,
    uint16_t* __restrict__ kc_o, uint16_t* __restrict__ vt_o)
{
  const int tid = threadIdx.x;
  const int w = tid >> 6, l = tid & 63;
  const int lg = l >> 4, lm = l & 15;
  const int row0 = blockIdx.x * 64 + w * 16;
  const int col0 = blockIdx.y * 64;

  short8 af[4];
  const float* Af = Av + (size_t)(row0 + lm) * 128 + lg * 8;
#pragma unroll
  for (int ks = 0; ks < 4; ++ks) {
    const f32x4 a0 = *(const f32x4*)(Af + ks * 32);
    const f32x4 a1 = *(const f32x4*)(Af + ks * 32 + 4);
    union { uint32_t u[4]; short8 s8; } cv;
    cv.u[0] = pk2(a0[0], a0[1]); cv.u[1] = pk2(a0[2], a0[3]);
    cv.u[2] = pk2(a1[0], a1[1]); cv.u[3] = pk2(a1[2], a1[3]);
    af[ks] = cv.s8;
  }

  f32x4 acc[4];
#pragma unroll
  for (int t = 0; t < 4; ++t) acc[t] = (f32x4){0.f, 0.f, 0.f, 0.f};

#pragma unroll
  for (int t = 0; t < 4; ++t) {
    const uint16_t* Bp = B1t + (size_t)(col0 + t * 16 + lm) * 128 + lg * 8;
#pragma unroll
    for (int ks = 0; ks < 4; ++ks)
      acc[t] = mfma32(af[ks], *(const short8*)(Bp + ks * 32), acc[t]);
  }

#pragma unroll
  for (int t = 0; t < 4; ++t) {
#pragma unroll
    for (int r = 0; r < 4; ++r) {
      const int row = row0 + lg * 4 + r;
      const int col = col0 + t * 16 + lm;
      const float v = acc[t][r];
      const int bb = row >> 11, ss = row & 2047;
      if (col < 128) {
        outb[(size_t)row * 128 + col] = f2bf(v);            // Q (pre-scaled)
      } else if (col < 256) {
        const int c = col - 128;
        kc_o[((size_t)((bb << 4) + (c >> 3)) * SEQ + ss) * 8 + (c & 7)] = f2bf(v);
      } else {
        const int c = col - 256;
        vt_o[((size_t)(bb * 128 + c)) * SEQ + ss] = f2bf(v);
      }
    }
  }
}

// ------------------------------------------------------------------
// Flash attention, 4 q-tiles/wave + 4-way key-split (r12 structure),
// WITHOUT per-tile s_setprio fences: the 24 setprio scheduling fences
// per chunk forced tile-serial execution (QK(t)->wait->exp(t)->PV(t));
// removing them lets the scheduler overlap tile t+1's QK MFMAs
// (matrix pipe) with tile t's exp2 burst (trans pipe) -- the trans
// pipe is the bottleneck (512 of ~600 cyc/chunk) and was 46% idle.
// Block = (b, h, 64 q rows); all 4 waves same q-tiles, key quarter
// kh = w (8 chunks of 64 keys). No-max softmax => key-quarters merge
// by pure addition via 16KB LDS; wave t merges tile t.
// Do NOT tighten launch_bounds (r6/r7 lesson).
// ------------------------------------------------------------------
__global__ __launch_bounds__(256, 4) void attn_kernel(
    const uint16_t* __restrict__ qb,   // [MROWS][128]  (pre-scaled Q)
    const uint16_t* __restrict__ kc,   // [B*NH][SEQ][8]
    const uint16_t* __restrict__ vt,   // [B*NH*8][SEQ]
    uint16_t* __restrict__ attn_o)     // [MROWS][128]
{
  __shared__ __attribute__((aligned(16))) float part[4][64][16];

  const int tid = threadIdx.x;
  const int w = tid >> 6, l = tid & 63;
  const int lg = l >> 4, lm = l & 15;
  int bid = blockIdx.x;
  bid = (bid & 7) * 256 + (bid >> 3);   // bijective XCD swizzle (2048 % 8 == 0)
  const int qc = bid & 31;              // SEQ/64 = 32 q-chunks
  const int bh = bid >> 5;
  const int b = bh >> 4, h = bh & 15;
  const int q0 = qc * 64;
  const int kh = w;                     // key quarter per wave

  const short8 zero8 = {0, 0, 0, 0, 0, 0, 0, 0};
  const f32x4 zero4 = {0.f, 0.f, 0.f, 0.f};
  const short ob = (short)0x3F80;  // bf16 1.0
  const short8 ones8 = {ob, ob, ob, ob, ob, ob, ob, ob};

  // Q fragments (4 tiles, same rows for all waves): lg==0 holds Q[q][d]
  short8 qf[4];
#pragma unroll
  for (int t = 0; t < 4; ++t) {
    qf[t] = zero8;
    if (lg == 0)
      qf[t] = *(const short8*)(qb + (size_t)(b * SEQ + q0 + t * 16 + lm) * DIM + h * HD);
  }

  // wave covers keys [kh*512, kh*512+512): 8 chunks of 64
  // permuted K base: tile-A row lm <- key 8*(lm>>2)+(lm&3)
  const uint16_t* kp = kc + (size_t)bh * SEQ * HD +
                       (kh * 512 + 8 * (lm >> 2) + (lm & 3)) * HD;
  // V: A-frag lane (lg, lm<8) holds Vt[d=lm][key + 8*lg + j]
  const uint16_t* vp = vt + (size_t)(bh * HD + (lm & 7)) * SEQ + kh * 512 + lg * 8;

  // named K/V double buffers
  short8 ka0 = zero8, ka1 = zero8, ka2 = zero8, ka3 = zero8;
  short8 kb0 = zero8, kb1 = zero8, kb2 = zero8, kb3 = zero8;
  const short8 vinit = (lm == 8) ? ones8 : zero8;
  short8 va0 = vinit, va1 = vinit, vb0 = vinit, vb1 = vinit;

  f32x4 acc[4];
#pragma unroll
  for (int t = 0; t < 4; ++t) acc[t] = zero4;

#define LK(R0, R1, R2, R3)                         \
  do { if (lg == 0) {                              \
    R0 = *(const short8*)(kp);                     \
    R1 = *(const short8*)(kp + 32);                \
    R2 = *(const short8*)(kp + 256);               \
    R3 = *(const short8*)(kp + 288); }             \
    kp += 512; } while (0)

#define LV(R0, R1)                                 \
  do { if (lm < HD) {                              \
    R0 = *(const short8*)(vp);                     \
    R1 = *(const short8*)(vp + 32); }              \
    vp += 64; } while (0)

#define PACKP(SA, SB, OUT)                                  \
  do { union { uint32_t u[4]; short8 s; } _t;               \
    _t.u[0] = pkt(fast_exp2(SA[0]), fast_exp2(SA[1]));      \
    _t.u[1] = pkt(fast_exp2(SA[2]), fast_exp2(SA[3]));      \
    _t.u[2] = pkt(fast_exp2(SB[0]), fast_exp2(SB[1]));      \
    _t.u[3] = pkt(fast_exp2(SB[2]), fast_exp2(SB[3]));      \
    OUT = _t.s; } while (0)

  // 4 q-tiles; NO setprio fences -> scheduler free to overlap tiles
#define COMPUTE(K0, K1, K2, K3, V0, V1)                     \
  do {                                                      \
    _Pragma("unroll")                                       \
    for (int t = 0; t < 4; ++t) {                           \
      f32x4 s0, s1, s2, s3;                                 \
      s0 = mfma32(K0, qf[t], zero4);                        \
      s1 = mfma32(K1, qf[t], zero4);                        \
      s2 = mfma32(K2, qf[t], zero4);                        \
      s3 = mfma32(K3, qf[t], zero4);                        \
      short8 p0, p1;                                        \
      PACKP(s0, s1, p0);                                    \
      PACKP(s2, s3, p1);                                    \
      acc[t] = mfma32(V0, p0, acc[t]);                      \
      acc[t] = mfma32(V1, p1, acc[t]);                      \
    }                                                       \
  } while (0)

  // software pipeline: 8 chunks of 64 keys; load i+1 before compute i
  LK(ka0, ka1, ka2, ka3); LV(va0, va1);
#pragma unroll 1
  for (int it = 0; it < 3; ++it) {
    LK(kb0, kb1, kb2, kb3); LV(vb0, vb1);
    COMPUTE(ka0, ka1, ka2, ka3, va0, va1);
    LK(ka0, ka1, ka2, ka3); LV(va0, va1);
    COMPUTE(kb0, kb1, kb2, kb3, vb0, vb1);
  }
  LK(kb0, kb1, kb2, kb3); LV(vb0, vb1);
  COMPUTE(ka0, ka1, ka2, ka3, va0, va1);
  COMPUTE(kb0, kb1, kb2, kb3, vb0, vb1);

#undef LK
#undef LV
#undef PACKP
#undef COMPUTE

  // ---- merge the four key-quarters (pure addition; no-max softmax) ----
#pragma unroll
  for (int t = 0; t < 4; ++t) *(f32x4*)&part[w][l][t * 4] = acc[t];
  __syncthreads();

  // wave w merges tile w across the 4 key-quarters
  {
    const f32x4 m = (*(const f32x4*)&part[0][l][w * 4] +
                     *(const f32x4*)&part[1][l][w * 4]) +
                    (*(const f32x4*)&part[2][l][w * 4] +
                     *(const f32x4*)&part[3][l][w * 4]);
    // row 8 (lane 32+lm, reg 0) holds sum(p) for q=lm
    const float inv = 1.0f / __shfl(m[0], 32 + lm);
    if (lg < 2) {
      const size_t o = (size_t)(b * SEQ + q0 + w * 16 + lm) * DIM + h * HD + lg * 4;
      *(uint32_t*)(attn_o + o)     = pk2(m[0] * inv, m[1] * inv);
      *(uint32_t*)(attn_o + o + 2) = pk2(m[2] * inv, m[3] * inv);
    }
  }
}

// ------------------------------------------------------------------
// Fused post-attention chain, column-split (r10-proven).
// Block = 16 rows x 8 waves (512 thr); grid = 512 blocks.
// ------------------------------------------------------------------
__global__ __launch_bounds__(512) void ffn_kernel(
    const uint16_t* __restrict__ attn_o,  // [MROWS][128] bf16
    const float* __restrict__ x,          // [MROWS][128] fp32
    const uint16_t* __restrict__ wo_t,    // [128][128]
    const uint16_t* __restrict__ w1_t,    // [384][128] (rows>=344 zero)
    const uint16_t* __restrict__ w3_t,    // [384][128]
    const uint16_t* __restrict__ w2_t,    // [128][352] (k>=344 zero)
    float* __restrict__ out)              // [MROWS][128] fp32
{
  __shared__ __attribute__((aligned(16))) uint16_t h_l[16][136];
  __shared__ __attribute__((aligned(16))) uint16_t u_l[16][360];

  const int tid = threadIdx.x;
  const int w = tid >> 6, l = tid & 63;
  const int lg = l >> 4, lm = l & 15;
  const int R0 = blockIdx.x * 16;

  // ---- stage A: h = x + attn @ wo  (wave w -> col-tile w) ----
  short8 af[4];
  const uint16_t* Ap = attn_o + (size_t)(R0 + lm) * 128 + lg * 8;
#pragma unroll
  for (int ks = 0; ks < 4; ++ks) af[ks] = *(const short8*)(Ap + ks * 32);

  float hreg[4];
  {
    f32x4 acc = (f32x4){0.f, 0.f, 0.f, 0.f};
    const uint16_t* Bp = wo_t + (size_t)(w * 16 + lm) * 128 + lg * 8;
#pragma unroll
    for (int ks = 0; ks < 4; ++ks)
      acc = mfma32(af[ks], *(const short8*)(Bp + ks * 32), acc);
#pragma unroll
    for (int r = 0; r < 4; ++r) {
      const float h = acc[r] + x[(size_t)(R0 + lg * 4 + r) * 128 + w * 16 + lm];
      hreg[r] = h;
      h_l[lg * 4 + r][w * 16 + lm] = f2bf(h);
    }
  }
  __syncthreads();

  // ---- stage B: u = silu(h@w1) * (h@w3)  (wave w -> ct = w, w+8, w+16) ----
  short8 af2[4];
#pragma unroll
  for (int ks = 0; ks < 4; ++ks)
    af2[ks] = *(const short8*)&h_l[lm][ks * 32 + lg * 8];

#pragma unroll
  for (int j = 0; j < 3; ++j) {
    const int ct = w + j * 8;
    if (ct >= 22) break;
    f32x4 ag = (f32x4){0.f, 0.f, 0.f, 0.f};
    f32x4 ae = (f32x4){0.f, 0.f, 0.f, 0.f};
    const uint16_t* B1p = w1_t + (size_t)(ct * 16 + lm) * 128 + lg * 8;
    const uint16_t* B3p = w3_t + (size_t)(ct * 16 + lm) * 128 + lg * 8;
#pragma unroll
    for (int ks = 0; ks < 4; ++ks) {
      ag = mfma32(af2[ks], *(const short8*)(B1p + ks * 32), ag);
      ae = mfma32(af2[ks], *(const short8*)(B3p + ks * 32), ae);
    }
#pragma unroll
    for (int r = 0; r < 4; ++r) {
      const float g = ag[r];
      const float u = g / (1.f + __expf(-g)) * ae[r];
      u_l[lg * 4 + r][ct * 16 + lm] = f2bf(u);
    }
  }
  __syncthreads();

  // ---- stage C: out = h + u @ w2  (wave w -> col-tile w) ----
  {
    f32x4 acc = (f32x4){0.f, 0.f, 0.f, 0.f};
    const uint16_t* Bp = w2_t + (size_t)(w * 16 + lm) * HIDP + lg * 8;
#pragma unroll
    for (int k2 = 0; k2 < 11; ++k2) {
      const short8 a3 = *(const short8*)&u_l[lm][k2 * 32 + lg * 8];
      acc = mfma32(a3, *(const short8*)(Bp + k2 * 32), acc);
    }
#pragma unroll
    for (int r = 0; r < 4; ++r)
      out[(size_t)(R0 + lg * 4 + r) * 128 + w * 16 + lm] = hreg[r] + acc[r];
  }
}

// ------------------------------------------------------------------
extern "C" void kernel_launch(void* const* d_in, const int* in_sizes, int n_in,
                              void* d_out, int out_size, void* d_ws, size_t ws_size,
                              hipStream_t stream) {
  const float* x  = (const float*)d_in[0];
  const float* wq = (const float*)d_in[1];
  const float* wk = (const float*)d_in[2];
  const float* wv = (const float*)d_in[3];
  const float* wo = (const float*)d_in[4];
  const float* w1 = (const float*)d_in[5];
  const float* w3 = (const float*)d_in[6];
  const float* w2 = (const float*)d_in[7];
  float* out = (float*)d_out;

  char* ws = (char*)d_ws;
  size_t off = 0;
  auto alloc = [&](size_t bytes) {
    size_t o = off;
    off += (bytes + 255) & ~(size_t)255;
    return o;
  };
  uint16_t* qkv_t  = (uint16_t*)(ws + alloc(384 * 128 * 2));
  uint16_t* wo_t   = (uint16_t*)(ws + alloc(128 * 128 * 2));
  uint16_t* w1_t   = (uint16_t*)(ws + alloc(384 * 128 * 2));
  uint16_t* w3_t   = (uint16_t*)(ws + alloc(384 * 128 * 2));
  uint16_t* w2_t   = (uint16_t*)(ws + alloc(128 * HIDP * 2));
  uint16_t* q_buf  = (uint16_t*)(ws + alloc((size_t)MROWS * DIM * 2));
  uint16_t* kc_b   = (uint16_t*)(ws + alloc((size_t)MROWS * DIM * 2));
  uint16_t* vt_b   = (uint16_t*)(ws + alloc((size_t)MROWS * DIM * 2));
  uint16_t* attn_o = (uint16_t*)(ws + alloc((size_t)MROWS * DIM * 2));

  prep_kernel<<<512, 256, 0, stream>>>(wq, wk, wv, wo, w1, w3, w2,
                                       qkv_t, wo_t, w1_t, w3_t, w2_t);
  // qkv = x @ [wq*log2e | wk | wv] -> q_buf, Kc, Vt
  qkv_gemm<<<dim3(MROWS / 64, 6), 256, 0, stream>>>(
      x, qkv_t, q_buf, kc_b, vt_b);
  // flash attention: 2048 blocks, 4 q-tiles/wave, 4-way key split
  attn_kernel<<<dim3(BATCH * NH * (SEQ / 64)), 256, 0, stream>>>(
      q_buf, kc_b, vt_b, attn_o);
  // fused: h = x + attn@wo; out = h + silu(h@w1)*(h@w3)@w2
  ffn_kernel<<<dim3(MROWS / 16), 512, 0, stream>>>(
      attn_o, x, wo_t, w1_t, w3_t, w2_t, out);
}

// Round 14
// 70.867 us; speedup vs baseline: 1.4795x; 1.0023x over previous
//
#include <hip/hip_runtime.h>
#include <hip/hip_bf16.h>
#include <stdint.h>

typedef __attribute__((ext_vector_type(8))) short short8;
typedef __attribute__((ext_vector_type(4))) float f32x4;

#define NTHREADS 256
#define DIM 128
#define NH 16
#define HD 8
#define HIDDEN 344
#define HIDP 352          // HIDDEN padded to multiple of 32 (22 col-tiles)
#define BATCH 4
#define SEQ 2048
#define MROWS (BATCH * SEQ)   // 8192
#define LOG2E 1.4426950408889634f

static __device__ __forceinline__ uint16_t f2bf(float f) {
  union { float f; uint32_t u; } v; v.f = f;
  uint32_t r = v.u + 0x7FFFu + ((v.u >> 16) & 1u);
  return (uint16_t)(r >> 16);
}
static __device__ __forceinline__ float fast_exp2(float x) {
#if __has_builtin(__builtin_amdgcn_exp2f)
  return __builtin_amdgcn_exp2f(x);
#else
  return exp2f(x);
#endif
}
// RNE pack: compiler emits v_cvt_pk_bf16_f32
static __device__ __forceinline__ uint32_t pk2(float lo, float hi) {
  union { __hip_bfloat162 b; uint32_t u; } c;
  c.b = __float22bfloat162_rn(make_float2(lo, hi));
  return c.u;
}
// truncating bf16x2 pack: one v_perm_b32 (p >= 0, error <= 2^-8 relative)
static __device__ __forceinline__ uint32_t pkt(float lo, float hi) {
  return __builtin_amdgcn_perm(__builtin_bit_cast(uint32_t, hi),
                               __builtin_bit_cast(uint32_t, lo), 0x07060302u);
}
static __device__ __forceinline__ f32x4 mfma32(short8 a, short8 b, f32x4 c) {
  return __builtin_amdgcn_mfma_f32_16x16x32_bf16(a, b, c, 0, 0, 0);
}

// ------------------------------------------------------------------
// prep: weights -> transposed bf16 Wt[n][k], padded where needed.
// wq rows pre-scaled by log2(e) so attention uses exp2 directly.
// ------------------------------------------------------------------
__global__ __launch_bounds__(256) void prep_kernel(
    const float* __restrict__ wq,
    const float* __restrict__ wk, const float* __restrict__ wv,
    const float* __restrict__ wo, const float* __restrict__ w1,
    const float* __restrict__ w3, const float* __restrict__ w2,
    uint16_t* __restrict__ qkv_t,
    uint16_t* __restrict__ wo_t,  uint16_t* __restrict__ w1_t,
    uint16_t* __restrict__ w3_t,  uint16_t* __restrict__ w2_t)
{
  const int nt  = gridDim.x * blockDim.x;
  const int tid = blockIdx.x * blockDim.x + threadIdx.x;
  for (int i = tid; i < 384 * 128; i += nt) {
    int n = i >> 7, k = i & 127;
    const float* w = (n < 128) ? wq : ((n < 256) ? wk : wv);
    const float s = (n < 128) ? LOG2E : 1.0f;
    qkv_t[i] = f2bf(w[k * 128 + (n & 127)] * s);
  }
  for (int i = tid; i < 128 * 128; i += nt) {
    int n = i >> 7, k = i & 127;
    wo_t[i] = f2bf(wo[k * 128 + n]);
  }
  for (int i = tid; i < 384 * 128; i += nt) {
    int n = i >> 7, k = i & 127;
    w1_t[i] = (n < HIDDEN) ? f2bf(w1[k * HIDDEN + n]) : (uint16_t)0;
    w3_t[i] = (n < HIDDEN) ? f2bf(w3[k * HIDDEN + n]) : (uint16_t)0;
  }
  for (int i = tid; i < 128 * HIDP; i += nt) {
    int n = i / HIDP, k = i - n * HIDP;
    w2_t[i] = (k < HIDDEN) ? f2bf(w2[k * 128 + n]) : (uint16_t)0;
  }
}

// ------------------------------------------------------------------
// Register-streaming QKV GEMM (r7-proven): no LDS, no barriers.
// ------------------------------------------------------------------
__global__ __launch_bounds__(256, 4) void qkv_gemm(
    const float* __restrict__ Av, const uint16_t* __restrict__ B1t,
    uint16_t* __restrict__ outb,
    uint16_t* __restrict__ kc_o, uint16_t* __restrict__ vt_o)
{
  const int tid = threadIdx.x;
  const int w = tid >> 6, l = tid & 63;
  const int lg = l >> 4, lm = l & 15;
  const int row0 = blockIdx.x * 64 + w * 16;
  const int col0 = blockIdx.y * 64;

  short8 af[4];
  const float* Af = Av + (size_t)(row0 + lm) * 128 + lg * 8;
#pragma unroll
  for (int ks = 0; ks < 4; ++ks) {
    const f32x4 a0 = *(const f32x4*)(Af + ks * 32);
    const f32x4 a1 = *(const f32x4*)(Af + ks * 32 + 4);
    union { uint32_t u[4]; short8 s8; } cv;
    cv.u[0] = pk2(a0[0], a0[1]); cv.u[1] = pk2(a0[2], a0[3]);
    cv.u[2] = pk2(a1[0], a1[1]); cv.u[3] = pk2(a1[2], a1[3]);
    af[ks] = cv.s8;
  }

  f32x4 acc[4];
#pragma unroll
  for (int t = 0; t < 4; ++t) acc[t] = (f32x4){0.f, 0.f, 0.f, 0.f};

#pragma unroll
  for (int t = 0; t < 4; ++t) {
    const uint16_t* Bp = B1t + (size_t)(col0 + t * 16 + lm) * 128 + lg * 8;
#pragma unroll
    for (int ks = 0; ks < 4; ++ks)
      acc[t] = mfma32(af[ks], *(const short8*)(Bp + ks * 32), acc[t]);
  }

#pragma unroll
  for (int t = 0; t < 4; ++t) {
#pragma unroll
    for (int r = 0; r < 4; ++r) {
      const int row = row0 + lg * 4 + r;
      const int col = col0 + t * 16 + lm;
      const float v = acc[t][r];
      const int bb = row >> 11, ss = row & 2047;
      if (col < 128) {
        outb[(size_t)row * 128 + col] = f2bf(v);            // Q (pre-scaled)
      } else if (col < 256) {
        const int c = col - 128;
        kc_o[((size_t)((bb << 4) + (c >> 3)) * SEQ + ss) * 8 + (c & 7)] = f2bf(v);
      } else {
        const int c = col - 256;
        vt_o[((size_t)(bb * 128 + c)) * SEQ + ss] = f2bf(v);
      }
    }
  }
}

// ------------------------------------------------------------------
// Flash attention, 4 q-tiles/wave + 4-way key-split, CROSS-TILE
// PIPELINED: per chunk, issue tile t+1's QK MFMAs (matrix pipe)
// before tile t's exp burst (trans pipe) so each wave keeps BOTH
// pipes fed (r13's tile-serial order made utilizations add: trans
// 13.7us + matrix ~12us + VALU ~4us ~= the whole 30+us runtime).
// Two named score buffers (sa/sb); K/V single-buffered with deferred
// prefetch (LK after last QK use, LV after last PV use) -- the freed
// 24 VGPRs pay for sa/sb. Working set ~110 < 128 cap of (256,4):
// safe per r6/r7 lesson (do NOT tighten launch_bounds).
// Block = (b, h, 64 q rows); all 4 waves same q-tiles, key quarter
// kh = w (8 chunks of 64 keys). No-max softmax => quarters merge by
// pure addition via 16KB LDS; wave t merges tile t. Tail prefetch
// reads one chunk past the buffers (adjacent ws allocations,
// read-only, unused).
// ------------------------------------------------------------------
__global__ __launch_bounds__(256, 4) void attn_kernel(
    const uint16_t* __restrict__ qb,   // [MROWS][128]  (pre-scaled Q)
    const uint16_t* __restrict__ kc,   // [B*NH][SEQ][8]
    const uint16_t* __restrict__ vt,   // [B*NH*8][SEQ]
    uint16_t* __restrict__ attn_o)     // [MROWS][128]
{
  __shared__ __attribute__((aligned(16))) float part[4][64][16];

  const int tid = threadIdx.x;
  const int w = tid >> 6, l = tid & 63;
  const int lg = l >> 4, lm = l & 15;
  int bid = blockIdx.x;
  bid = (bid & 7) * 256 + (bid >> 3);   // bijective XCD swizzle (2048 % 8 == 0)
  const int qc = bid & 31;              // SEQ/64 = 32 q-chunks
  const int bh = bid >> 5;
  const int b = bh >> 4, h = bh & 15;
  const int q0 = qc * 64;
  const int kh = w;                     // key quarter per wave

  const short8 zero8 = {0, 0, 0, 0, 0, 0, 0, 0};
  const f32x4 zero4 = {0.f, 0.f, 0.f, 0.f};
  const short ob = (short)0x3F80;  // bf16 1.0
  const short8 ones8 = {ob, ob, ob, ob, ob, ob, ob, ob};

  // Q fragments (4 tiles, same rows for all waves): lg==0 holds Q[q][d]
  short8 qf0 = zero8, qf1 = zero8, qf2 = zero8, qf3 = zero8;
  if (lg == 0) {
    const uint16_t* qp = qb + (size_t)(b * SEQ + q0 + lm) * DIM + h * HD;
    qf0 = *(const short8*)(qp);
    qf1 = *(const short8*)(qp + 16 * DIM);
    qf2 = *(const short8*)(qp + 32 * DIM);
    qf3 = *(const short8*)(qp + 48 * DIM);
  }

  // wave covers keys [kh*512, kh*512+512): 8 chunks of 64
  // permuted K base: tile-A row lm <- key 8*(lm>>2)+(lm&3)
  const uint16_t* kp = kc + (size_t)bh * SEQ * HD +
                       (kh * 512 + 8 * (lm >> 2) + (lm & 3)) * HD;
  // V: A-frag lane (lg, lm<8) holds Vt[d=lm][key + 8*lg + j]
  const uint16_t* vp = vt + (size_t)(bh * HD + (lm & 7)) * SEQ + kh * 512 + lg * 8;

  // single-buffer K/V, deferred prefetch
  short8 k0 = zero8, k1 = zero8, k2 = zero8, k3 = zero8;
  short8 v0 = (lm == 8) ? ones8 : zero8;
  short8 v1 = v0;

  f32x4 acc0 = zero4, acc1 = zero4, acc2 = zero4, acc3 = zero4;

#define LK()                                       \
  do { if (lg == 0) {                              \
    k0 = *(const short8*)(kp);                     \
    k1 = *(const short8*)(kp + 32);                \
    k2 = *(const short8*)(kp + 256);               \
    k3 = *(const short8*)(kp + 288); }             \
    kp += 512; } while (0)

#define LV()                                       \
  do { if (lm < HD) {                              \
    v0 = *(const short8*)(vp);                     \
    v1 = *(const short8*)(vp + 32); }              \
    vp += 64; } while (0)

#define PACKP(SA, SB, OUT)                                  \
  do { union { uint32_t u[4]; short8 s; } _t;               \
    _t.u[0] = pkt(fast_exp2(SA[0]), fast_exp2(SA[1]));      \
    _t.u[1] = pkt(fast_exp2(SA[2]), fast_exp2(SA[3]));      \
    _t.u[2] = pkt(fast_exp2(SB[0]), fast_exp2(SB[1]));      \
    _t.u[3] = pkt(fast_exp2(SB[2]), fast_exp2(SB[3]));      \
    OUT = _t.s; } while (0)

  // preload chunk 0
  LK();
  LV();

#pragma unroll 1
  for (int it = 0; it < 8; ++it) {
    short8 p0, p1;
    // tile0 & tile1 QK -> sa, sb (matrix pipe fills ahead)
    f32x4 sa0 = mfma32(k0, qf0, zero4);
    f32x4 sa1 = mfma32(k1, qf0, zero4);
    f32x4 sa2 = mfma32(k2, qf0, zero4);
    f32x4 sa3 = mfma32(k3, qf0, zero4);
    f32x4 sb0 = mfma32(k0, qf1, zero4);
    f32x4 sb1 = mfma32(k1, qf1, zero4);
    f32x4 sb2 = mfma32(k2, qf1, zero4);
    f32x4 sb3 = mfma32(k3, qf1, zero4);
    // tile0 exp+pack (trans pipe) overlaps tile1 QK in matrix pipe
    PACKP(sa0, sa1, p0);
    PACKP(sa2, sa3, p1);
    acc0 = mfma32(v0, p0, acc0);
    acc0 = mfma32(v1, p1, acc0);
    // tile2 QK reuses sa while tile1 exps run
    sa0 = mfma32(k0, qf2, zero4);
    sa1 = mfma32(k1, qf2, zero4);
    sa2 = mfma32(k2, qf2, zero4);
    sa3 = mfma32(k3, qf2, zero4);
    PACKP(sb0, sb1, p0);
    PACKP(sb2, sb3, p1);
    acc1 = mfma32(v0, p0, acc1);
    acc1 = mfma32(v1, p1, acc1);
    // tile3 QK reuses sb; after this K regs are dead -> prefetch
    sb0 = mfma32(k0, qf3, zero4);
    sb1 = mfma32(k1, qf3, zero4);
    sb2 = mfma32(k2, qf3, zero4);
    sb3 = mfma32(k3, qf3, zero4);
    LK();   // next chunk's K (WAR-safe: all QK issued)
    PACKP(sa0, sa1, p0);
    PACKP(sa2, sa3, p1);
    acc2 = mfma32(v0, p0, acc2);
    acc2 = mfma32(v1, p1, acc2);
    PACKP(sb0, sb1, p0);
    PACKP(sb2, sb3, p1);
    acc3 = mfma32(v0, p0, acc3);
    acc3 = mfma32(v1, p1, acc3);
    LV();   // next chunk's V (V regs dead after acc3 PV)
  }

#undef LK
#undef LV
#undef PACKP

  // ---- merge the four key-quarters (pure addition; no-max softmax) ----
  *(f32x4*)&part[w][l][0]  = acc0;
  *(f32x4*)&part[w][l][4]  = acc1;
  *(f32x4*)&part[w][l][8]  = acc2;
  *(f32x4*)&part[w][l][12] = acc3;
  __syncthreads();

  // wave w merges tile w across the 4 key-quarters
  {
    const f32x4 m = (*(const f32x4*)&part[0][l][w * 4] +
                     *(const f32x4*)&part[1][l][w * 4]) +
                    (*(const f32x4*)&part[2][l][w * 4] +
                     *(const f32x4*)&part[3][l][w * 4]);
    // row 8 (lane 32+lm, reg 0) holds sum(p) for q=lm
    const float inv = 1.0f / __shfl(m[0], 32 + lm);
    if (lg < 2) {
      const size_t o = (size_t)(b * SEQ + q0 + w * 16 + lm) * DIM + h * HD + lg * 4;
      *(uint32_t*)(attn_o + o)     = pk2(m[0] * inv, m[1] * inv);
      *(uint32_t*)(attn_o + o + 2) = pk2(m[2] * inv, m[3] * inv);
    }
  }
}

// ------------------------------------------------------------------
// Fused post-attention chain, column-split (r10-proven).
// Block = 16 rows x 8 waves (512 thr); grid = 512 blocks.
// ------------------------------------------------------------------
__global__ __launch_bounds__(512) void ffn_kernel(
    const uint16_t* __restrict__ attn_o,  // [MROWS][128] bf16
    const float* __restrict__ x,          // [MROWS][128] fp32
    const uint16_t* __restrict__ wo_t,    // [128][128]
    const uint16_t* __restrict__ w1_t,    // [384][128] (rows>=344 zero)
    const uint16_t* __restrict__ w3_t,    // [384][128]
    const uint16_t* __restrict__ w2_t,    // [128][352] (k>=344 zero)
    float* __restrict__ out)              // [MROWS][128] fp32
{
  __shared__ __attribute__((aligned(16))) uint16_t h_l[16][136];
  __shared__ __attribute__((aligned(16))) uint16_t u_l[16][360];

  const int tid = threadIdx.x;
  const int w = tid >> 6, l = tid & 63;
  const int lg = l >> 4, lm = l & 15;
  const int R0 = blockIdx.x * 16;

  // ---- stage A: h = x + attn @ wo  (wave w -> col-tile w) ----
  short8 af[4];
  const uint16_t* Ap = attn_o + (size_t)(R0 + lm) * 128 + lg * 8;
#pragma unroll
  for (int ks = 0; ks < 4; ++ks) af[ks] = *(const short8*)(Ap + ks * 32);

  float hreg[4];
  {
    f32x4 acc = (f32x4){0.f, 0.f, 0.f, 0.f};
    const uint16_t* Bp = wo_t + (size_t)(w * 16 + lm) * 128 + lg * 8;
#pragma unroll
    for (int ks = 0; ks < 4; ++ks)
      acc = mfma32(af[ks], *(const short8*)(Bp + ks * 32), acc);
#pragma unroll
    for (int r = 0; r < 4; ++r) {
      const float h = acc[r] + x[(size_t)(R0 + lg * 4 + r) * 128 + w * 16 + lm];
      hreg[r] = h;
      h_l[lg * 4 + r][w * 16 + lm] = f2bf(h);
    }
  }
  __syncthreads();

  // ---- stage B: u = silu(h@w1) * (h@w3)  (wave w -> ct = w, w+8, w+16) ----
  short8 af2[4];
#pragma unroll
  for (int ks = 0; ks < 4; ++ks)
    af2[ks] = *(const short8*)&h_l[lm][ks * 32 + lg * 8];

#pragma unroll
  for (int j = 0; j < 3; ++j) {
    const int ct = w + j * 8;
    if (ct >= 22) break;
    f32x4 ag = (f32x4){0.f, 0.f, 0.f, 0.f};
    f32x4 ae = (f32x4){0.f, 0.f, 0.f, 0.f};
    const uint16_t* B1p = w1_t + (size_t)(ct * 16 + lm) * 128 + lg * 8;
    const uint16_t* B3p = w3_t + (size_t)(ct * 16 + lm) * 128 + lg * 8;
#pragma unroll
    for (int ks = 0; ks < 4; ++ks) {
      ag = mfma32(af2[ks], *(const short8*)(B1p + ks * 32), ag);
      ae = mfma32(af2[ks], *(const short8*)(B3p + ks * 32), ae);
    }
#pragma unroll
    for (int r = 0; r < 4; ++r) {
      const float g = ag[r];
      const float u = g / (1.f + __expf(-g)) * ae[r];
      u_l[lg * 4 + r][ct * 16 + lm] = f2bf(u);
    }
  }
  __syncthreads();

  // ---- stage C: out = h + u @ w2  (wave w -> col-tile w) ----
  {
    f32x4 acc = (f32x4){0.f, 0.f, 0.f, 0.f};
    const uint16_t* Bp = w2_t + (size_t)(w * 16 + lm) * HIDP + lg * 8;
#pragma unroll
    for (int k2 = 0; k2 < 11; ++k2) {
      const short8 a3 = *(const short8*)&u_l[lm][k2 * 32 + lg * 8];
      acc = mfma32(a3, *(const short8*)(Bp + k2 * 32), acc);
    }
#pragma unroll
    for (int r = 0; r < 4; ++r)
      out[(size_t)(R0 + lg * 4 + r) * 128 + w * 16 + lm] = hreg[r] + acc[r];
  }
}

// ------------------------------------------------------------------
extern "C" void kernel_launch(void* const* d_in, const int* in_sizes, int n_in,
                              void* d_out, int out_size, void* d_ws, size_t ws_size,
                              hipStream_t stream) {
  const float* x  = (const float*)d_in[0];
  const float* wq = (const float*)d_in[1];
  const float* wk = (const float*)d_in[2];
  const float* wv = (const float*)d_in[3];
  const float* wo = (const float*)d_in[4];
  const float* w1 = (const float*)d_in[5];
  const float* w3 = (const float*)d_in[6];
  const float* w2 = (const float*)d_in[7];
  float* out = (float*)d_out;

  char* ws = (char*)d_ws;
  size_t off = 0;
  auto alloc = [&](size_t bytes) {
    size_t o = off;
    off += (bytes + 255) & ~(size_t)255;
    return o;
  };
  uint16_t* qkv_t  = (uint16_t*)(ws + alloc(384 * 128 * 2));
  uint16_t* wo_t   = (uint16_t*)(ws + alloc(128 * 128 * 2));
  uint16_t* w1_t   = (uint16_t*)(ws + alloc(384 * 128 * 2));
  uint16_t* w3_t   = (uint16_t*)(ws + alloc(384 * 128 * 2));
  uint16_t* w2_t   = (uint16_t*)(ws + alloc(128 * HIDP * 2));
  uint16_t* q_buf  = (uint16_t*)(ws + alloc((size_t)MROWS * DIM * 2));
  uint16_t* kc_b   = (uint16_t*)(ws + alloc((size_t)MROWS * DIM * 2));
  uint16_t* vt_b   = (uint16_t*)(ws + alloc((size_t)MROWS * DIM * 2));
  uint16_t* attn_o = (uint16_t*)(ws + alloc((size_t)MROWS * DIM * 2));

  prep_kernel<<<512, 256, 0, stream>>>(wq, wk, wv, wo, w1, w3, w2,
                                       qkv_t, wo_t, w1_t, w3_t, w2_t);
  // qkv = x @ [wq*log2e | wk | wv] -> q_buf, Kc, Vt
  qkv_gemm<<<dim3(MROWS / 64, 6), 256, 0, stream>>>(
      x, qkv_t, q_buf, kc_b, vt_b);
  // flash attention: 2048 blocks, 4 q-tiles/wave, 4-way key split,
  // cross-tile pipelined
  attn_kernel<<<dim3(BATCH * NH * (SEQ / 64)), 256, 0, stream>>>(
      q_buf, kc_b, vt_b, attn_o);
  // fused: h = x + attn@wo; out = h + silu(h@w1)*(h@w3)@w2
  ffn_kernel<<<dim3(MROWS / 16), 512, 0, stream>>>(
      attn_o, x, wo_t, w1_t, w3_t, w2_t, out);
}